// Round 6
// baseline (710.696 us; speedup 1.0000x reference)
//
#include <hip/hip_runtime.h>
#include <hip/hip_bf16.h>
#include <math.h>

// ---------------- constants ----------------
#define B_SZ 4
#define DIM 384
#define HEADS 6
#define HD 64
#define NTOK 4096          // B*32*32
#define WS 14
#define NWIN 36            // B * 9
#define WTOK 196           // 14*14

typedef unsigned short u16;
typedef __bf16 bf16_t;
typedef bf16_t bf16x8 __attribute__((ext_vector_type(8)));
typedef float f32x4 __attribute__((ext_vector_type(4)));

__device__ __forceinline__ float bf2f(unsigned u) { return __uint_as_float(u << 16); }
__device__ __forceinline__ u16 f2bf(float f) {
    unsigned u = __float_as_uint(f);
    unsigned r = (u + 0x7fffu + ((u >> 16) & 1u)) >> 16;
    return (u16)r;
}
// packed RNE f32x2 -> bf16x2 (hardware v_cvt_pk_bf16_f32 on gfx950)
__device__ __forceinline__ unsigned pk2bf(float a, float b) {
    __hip_bfloat162 h = __float22bfloat162_rn(make_float2(a, b));
    unsigned r; __builtin_memcpy(&r, &h, 4); return r;
}

// async global->LDS, 16B per lane, wave-uniform LDS base + lane*16
__device__ __forceinline__ void ldsload16(const u16* g, u16* l) {
    __builtin_amdgcn_global_load_lds(
        (const __attribute__((address_space(1))) unsigned int*)g,
        (__attribute__((address_space(3))) unsigned int*)l, 16, 0, 0);
}

__device__ __forceinline__ int swz(int r) { return (r ^ (r >> 2)) & 3; }

// ---------------- bicubic helper ----------------
__device__ inline float cubic_keys(float x) {
    x = fabsf(x);
    if (x <= 1.f) return ((1.5f * x - 2.5f) * x) * x + 1.f;
    if (x < 2.f)  return ((-0.5f * x + 2.5f) * x - 4.f) * x + 2.f;
    return 0.f;
}

// ---------------- one-shot setup (x4 vectorized) -----------------------------
__global__ __launch_bounds__(256) void setup_kernel(
        const float* __restrict__ p0, const float* __restrict__ p1,
        const float* __restrict__ p2, const float* __restrict__ p3,
        const float* __restrict__ p4, const float* __restrict__ p5,
        u16* __restrict__ wb, const float* __restrict__ pe,
        float* __restrict__ posr, const float* __restrict__ x,
        u16* __restrict__ col) {
    int i = (blockIdx.x * 256 + threadIdx.x) * 4;
    if (i < 10918656) {
        const float* s; int off;
        if      (i <   294912) { s = p0; off = 0; }
        else if (i <  2949120) { s = p1; off = 294912; }
        else if (i <  3833856) { s = p2; off = 2949120; }
        else if (i <  7372800) { s = p3; off = 3833856; }
        else if (i < 10911744) { s = p4; off = 7372800; }
        else                   { s = p5; off = 10911744; }
        float4 v = *(const float4*)(s + (i - off));
        u16 o[4] = { f2bf(v.x), f2bf(v.y), f2bf(v.z), f2bf(v.w) };
        *(uint2*)(wb + i) = *(const uint2*)o;
        return;
    }
    i -= 10918656;
    if (i < 393216) {
        int c = i % 384;
        int g = i / 384;
        int gy = g / 32, gx = g % 32;
        float wy[14], wx[14];
        float sy = (gy + 0.5f) * (14.f / 32.f) - 0.5f;
        float sx = (gx + 0.5f) * (14.f / 32.f) - 0.5f;
        float toty = 0.f, totx = 0.f;
        #pragma unroll
        for (int k = 0; k < 14; ++k) {
            wy[k] = cubic_keys(sy - (float)k); toty += wy[k];
            wx[k] = cubic_keys(sx - (float)k); totx += wx[k];
        }
        float4 acc = {0.f, 0.f, 0.f, 0.f};
        #pragma unroll 1
        for (int iy = 0; iy < 14; ++iy) {
            if (wy[iy] == 0.f) continue;
            float4 row = {0.f, 0.f, 0.f, 0.f};
            for (int ix = 0; ix < 14; ++ix) {
                if (wx[ix] == 0.f) continue;
                float4 pv = *(const float4*)(pe + (iy * 14 + ix) * 384 + c);
                row.x += wx[ix] * pv.x; row.y += wx[ix] * pv.y;
                row.z += wx[ix] * pv.z; row.w += wx[ix] * pv.w;
            }
            acc.x += wy[iy] * row.x; acc.y += wy[iy] * row.y;
            acc.z += wy[iy] * row.z; acc.w += wy[iy] * row.w;
        }
        float inv = 1.f / (toty * totx);
        acc.x *= inv; acc.y *= inv; acc.z *= inv; acc.w *= inv;
        *(float4*)(posr + i) = acc;
        return;
    }
    i -= 393216;
    if (i < 3145728) {
        int kk = i % 768;
        int p  = i / 768;
        int b  = p / 1024;
        int ph = (p % 1024) / 32;
        int pw = p % 32;
        int c = kk / 256;
        int r = kk % 256;
        int ii = r / 16, j = r % 16;
        float4 v = *(const float4*)(x + (size_t)b * 3 * 512 * 512 +
                                    (size_t)c * 512 * 512 +
                                    (size_t)(ph * 16 + ii) * 512 + (pw * 16 + j));
        u16 o[4] = { f2bf(v.x), f2bf(v.y), f2bf(v.z), f2bf(v.w) };
        *(uint2*)(col + i) = *(const uint2*)o;
    }
}

// ---------------- slim LN kernel: y (f32) -> lnb (bf16) ----------------------
// 256 threads = 4 tokens/block (1 wave per token); used after fc2 only
__global__ __launch_bounds__(256) void ln_kernel(const float* __restrict__ y,
        const float* __restrict__ lw, const float* __restrict__ lb,
        u16* __restrict__ lnout)
{
    int tok = blockIdx.x * 4 + (threadIdx.x >> 6);
    int t = threadIdx.x & 63;
    size_t base = (size_t)tok * 384;
    float v[6];
    float s = 0.f;
    #pragma unroll
    for (int i = 0; i < 6; ++i) {
        v[i] = y[base + t + 64 * i]; s += v[i];
    }
    #pragma unroll
    for (int off = 32; off > 0; off >>= 1) s += __shfl_xor(s, off);
    float mean = s * (1.f / 384.f);
    float vs = 0.f;
    #pragma unroll
    for (int i = 0; i < 6; ++i) { float d = v[i] - mean; vs += d * d; }
    #pragma unroll
    for (int off = 32; off > 0; off >>= 1) vs += __shfl_xor(vs, off);
    float inv = rsqrtf(vs * (1.f / 384.f) + 1e-5f);
    u16* orow = lnout + base;
    #pragma unroll
    for (int i = 0; i < 6; ++i) {
        int c = t + 64 * i;
        orow[c] = f2bf((v[i] - mean) * inv * lw[c] + lb[c]);
    }
}

// ---------------- coalesced NHWC(f32 y) -> NCHW out via LDS transpose --------
__global__ __launch_bounds__(256) void out_transpose(const float* __restrict__ y,
        float* __restrict__ outT)
{
    __shared__ float T[64][65];
    int c0 = blockIdx.x * 64, m0 = blockIdx.y * 64;
    int t = threadIdx.x;
    int cl = t & 63, wv = t >> 6;
    #pragma unroll
    for (int r = 0; r < 16; ++r) {
        int ml = wv * 16 + r;
        T[ml][cl] = y[(size_t)(m0 + ml) * 384 + c0 + cl];
    }
    __syncthreads();
    int b = m0 >> 10, g0 = m0 & 1023;
    int gl = t & 63;
    #pragma unroll
    for (int r = 0; r < 16; ++r) {
        int ccl = wv * 16 + r;
        outT[((size_t)(b * 384 + c0 + ccl)) * 1024 + g0 + gl] = T[gl][ccl];
    }
}

// ---------------- MFMA bf16 GEMM v4: BM=128, BN=64, BK=64, dbuf --------------
// used for fc1 (GELU, bf16 out); grid 768 = 3/CU exact
__global__ __launch_bounds__(256) void mfma_gemm4(
        const u16* __restrict__ A, const u16* __restrict__ Wt,
        const float* __restrict__ bias,
        u16* __restrict__ outb,
        int M, int N, int K, int act)
{
    __shared__ u16 As[2][8192];
    __shared__ u16 Bs[2][4096];
    int t = threadIdx.x;
    int lane = t & 63, wave = t >> 6;
    int wm = (wave >> 1) * 64, wn = (wave & 1) * 32;
    int m0 = blockIdx.y * 128, n0 = blockIdx.x * 64;

    int r0 = t >> 2,        c0 = ((t & 3) ^ swz(t >> 2)) * 8;
    int r1 = 64 + (t >> 2), c1 = ((t & 3) ^ swz(64 + (t >> 2))) * 8;
    const u16* a0 = A + (size_t)(m0 + r0) * K + c0;
    const u16* a1 = A + (size_t)(m0 + r1) * K + c1;
    const u16* b0 = Wt + (size_t)(n0 + r0) * K + c0;

    auto stage = [&](int k0, int buf) {
        ldsload16(a0 + k0,      &As[buf][wave * 512]);
        ldsload16(a1 + k0,      &As[buf][2048 + wave * 512]);
        ldsload16(b0 + k0,      &Bs[buf][wave * 512]);
        ldsload16(a0 + k0 + 32, &As[buf][4096 + wave * 512]);
        ldsload16(a1 + k0 + 32, &As[buf][6144 + wave * 512]);
        ldsload16(b0 + k0 + 32, &Bs[buf][2048 + wave * 512]);
    };

    f32x4 acc[4][2] = {};
    int row_a = wm + (lane & 15);
    int row_b = wn + (lane & 15);
    int lq = lane >> 4;
    int nchunks = K / 64;

    stage(0, 0);
    __syncthreads();

    for (int ci = 0; ci < nchunks; ++ci) {
        int p = ci & 1;
        bool pref = (ci + 1 < nchunks);
        if (pref) stage((ci + 1) * 64, 1 - p);
        #pragma unroll
        for (int hf = 0; hf < 2; ++hf) {
            bf16x8 af[4], bfr[2];
            #pragma unroll
            for (int i = 0; i < 4; ++i) {
                int r = row_a + i * 16;
                af[i] = *(const bf16x8*)&As[p][hf * 4096 + r * 32 + ((lq ^ swz(r)) * 8)];
            }
            #pragma unroll
            for (int j = 0; j < 2; ++j) {
                int r = row_b + j * 16;
                bfr[j] = *(const bf16x8*)&Bs[p][hf * 2048 + r * 32 + ((lq ^ swz(r)) * 8)];
            }
            #pragma unroll
            for (int i = 0; i < 4; ++i)
                #pragma unroll
                for (int j = 0; j < 2; ++j)
                    acc[i][j] = __builtin_amdgcn_mfma_f32_16x16x32_bf16(
                        af[i], bfr[j], acc[i][j], 0, 0, 0);
        }
        if (pref) __syncthreads();
    }

    int colq = lane & 15, rowq = (lane >> 4) * 4;
    #pragma unroll
    for (int i = 0; i < 4; ++i) {
        #pragma unroll
        for (int rr = 0; rr < 4; ++rr) {
            int m = m0 + wm + i * 16 + rowq + rr;
            size_t mo = (size_t)m * N;
            #pragma unroll
            for (int j = 0; j < 2; ++j) {
                int n = n0 + wn + j * 16 + colq;
                float v = acc[i][j][rr] + bias[n];
                if (act)  v = 0.5f * v * (1.f + erff(v * 0.70710678118654752f));
                outb[mo + n] = f2bf(v);
            }
        }
    }
}

// ---------------- MFMA bf16 GEMM 64x64, bf16 out: used for qkv ---------------
// grid (1152/64, 4096/64) = (18, 64) = 1152 blocks = 4.5/CU (balanced), 32KB LDS
__global__ __launch_bounds__(256) void mfma_gemm64b(
        const u16* __restrict__ A, const u16* __restrict__ Wt,
        const float* __restrict__ bias, u16* __restrict__ outb,
        int M, int N, int K)
{
    __shared__ u16 As[2][4096];
    __shared__ u16 Bs[2][4096];
    int t = threadIdx.x;
    int lane = t & 63, wave = t >> 6;
    int wm = (wave >> 1) * 32, wn = (wave & 1) * 32;
    int m0 = blockIdx.y * 64, n0 = blockIdx.x * 64;

    int r0 = t >> 2, c0 = ((t & 3) ^ swz(t >> 2)) * 8;
    const u16* a0 = A + (size_t)(m0 + r0) * K + c0;
    const u16* b0 = Wt + (size_t)(n0 + r0) * K + c0;

    auto stage = [&](int k0, int buf) {
        ldsload16(a0 + k0,      &As[buf][wave * 512]);
        ldsload16(b0 + k0,      &Bs[buf][wave * 512]);
        ldsload16(a0 + k0 + 32, &As[buf][2048 + wave * 512]);
        ldsload16(b0 + k0 + 32, &Bs[buf][2048 + wave * 512]);
    };

    f32x4 acc[2][2] = {};
    int row_a = wm + (lane & 15);
    int row_b = wn + (lane & 15);
    int lq = lane >> 4;
    int nchunks = K / 64;

    stage(0, 0);
    __syncthreads();

    for (int ci = 0; ci < nchunks; ++ci) {
        int p = ci & 1;
        bool pref = (ci + 1 < nchunks);
        if (pref) stage((ci + 1) * 64, 1 - p);
        #pragma unroll
        for (int hf = 0; hf < 2; ++hf) {
            bf16x8 af[2], bfr[2];
            #pragma unroll
            for (int i = 0; i < 2; ++i) {
                int r = row_a + i * 16;
                af[i] = *(const bf16x8*)&As[p][hf * 2048 + r * 32 + ((lq ^ swz(r)) * 8)];
            }
            #pragma unroll
            for (int j = 0; j < 2; ++j) {
                int r = row_b + j * 16;
                bfr[j] = *(const bf16x8*)&Bs[p][hf * 2048 + r * 32 + ((lq ^ swz(r)) * 8)];
            }
            #pragma unroll
            for (int i = 0; i < 2; ++i)
                #pragma unroll
                for (int j = 0; j < 2; ++j)
                    acc[i][j] = __builtin_amdgcn_mfma_f32_16x16x32_bf16(
                        af[i], bfr[j], acc[i][j], 0, 0, 0);
        }
        if (pref) __syncthreads();
    }

    int colq = lane & 15, rowq = (lane >> 4) * 4;
    #pragma unroll
    for (int i = 0; i < 2; ++i) {
        #pragma unroll
        for (int rr = 0; rr < 4; ++rr) {
            int m = m0 + wm + i * 16 + rowq + rr;
            size_t mo = (size_t)m * N;
            #pragma unroll
            for (int j = 0; j < 2; ++j) {
                int n = n0 + wn + j * 16 + colq;
                outb[mo + n] = f2bf(acc[i][j][rr] + bias[n]);
            }
        }
    }
}

// ---------------- MFMA bf16 GEMM 16x384 full-row + fused residual + LN -------
// block owns 16 complete rows: epilogue does bias (+posr) (+y) -> y (f32),
// then block-wide LayerNorm -> lnout (bf16). grid M/16 = 256 = 1/CU exact.
// LDS: Bs 2x48KB + As 2x2KB = 100KB -> 1 block/CU (L2-BW streaming kernel).
__global__ __launch_bounds__(256) void mfma_gemm_fr(
        const u16* __restrict__ A, const u16* __restrict__ Wt,
        const float* __restrict__ bias, const float* __restrict__ posr,
        float* __restrict__ y, int addy,
        const float* __restrict__ lw, const float* __restrict__ lb,
        u16* __restrict__ lnout, int M, int K)
{
    __shared__ u16 As[2][1024];     // [buf][half(512)] : 16 rows x 32 k
    __shared__ u16 Bs[2][24576];    // [buf][half(12288)] : 384 rows x 32 k
    __shared__ float red[4][16];
    int t = threadIdx.x;
    int lane = t & 63, wave = t >> 6;
    int quad = lane >> 4, l15 = lane & 15;
    int m0 = blockIdx.x * 16;

    // A staging (waves 0/1): 16 rows x 32 k per half, linear lane order
    int arow = lane >> 2;
    int acol8 = (lane & 3) ^ swz(arow);
    const u16* asrc = A + (size_t)(m0 + arow) * K + acol8 * 8 + (wave == 1 ? 32 : 0);

    // B staging: 6 row-groups x 2 halves, pre-swizzled global source
    const u16* bsrc[6];
    #pragma unroll
    for (int j = 0; j < 6; ++j) {
        int row = j * 64 + (t >> 2);
        int col8 = (t & 3) ^ swz(row);
        bsrc[j] = Wt + (size_t)row * K + col8 * 8;
    }

    auto stage = [&](int k0, int buf) {
        #pragma unroll
        for (int j = 0; j < 6; ++j) {
            ldsload16(bsrc[j] + k0,      &Bs[buf][(j * 64 + wave * 16) * 32]);
            ldsload16(bsrc[j] + k0 + 32, &Bs[buf][12288 + (j * 64 + wave * 16) * 32]);
        }
        if (wave == 0) ldsload16(asrc + k0, &As[buf][0]);
        if (wave == 1) ldsload16(asrc + k0, &As[buf][512]);
    };

    f32x4 acc[6] = {};
    int nchunks = K / 64;

    stage(0, 0);
    __syncthreads();

    for (int ci = 0; ci < nchunks; ++ci) {
        int p = ci & 1;
        bool pref = (ci + 1 < nchunks);
        if (pref) stage((ci + 1) * 64, 1 - p);
        #pragma unroll
        for (int hf = 0; hf < 2; ++hf) {
            bf16x8 af = *(const bf16x8*)&As[p][hf * 512 + l15 * 32 +
                                               ((quad ^ swz(l15)) * 8)];
            #pragma unroll
            for (int ct = 0; ct < 6; ++ct) {
                int rb = wave * 96 + ct * 16 + l15;
                bf16x8 bfr = *(const bf16x8*)&Bs[p][hf * 12288 + rb * 32 +
                                                    ((quad ^ swz(rb)) * 8)];
                acc[ct] = __builtin_amdgcn_mfma_f32_16x16x32_bf16(
                    af, bfr, acc[ct], 0, 0, 0);
            }
        }
        if (pref) __syncthreads();
    }

    // ---- epilogue: v = acc + bias (+posr) (+y); write y; block-wide LN ----
    int colq = l15, rowq = quad * 4;
    float v[6][4];
    float s[4] = {0.f, 0.f, 0.f, 0.f};
    #pragma unroll
    for (int ct = 0; ct < 6; ++ct) {
        int n = wave * 96 + ct * 16 + colq;
        float bn = bias[n];
        #pragma unroll
        for (int rr = 0; rr < 4; ++rr) {
            int m = m0 + rowq + rr;
            float val = acc[ct][rr] + bn;
            if (posr) val += posr[(size_t)(m & 1023) * 384 + n];
            if (addy) val += y[(size_t)m * 384 + n];
            v[ct][rr] = val;
            s[rr] += val;
            y[(size_t)m * 384 + n] = val;
        }
    }
    // row sums across the 16 lanes of each col-group (cols of this wave)
    #pragma unroll
    for (int off = 1; off < 16; off <<= 1)
        #pragma unroll
        for (int rr = 0; rr < 4; ++rr) s[rr] += __shfl_xor(s[rr], off);
    if (l15 == 0) {
        #pragma unroll
        for (int rr = 0; rr < 4; ++rr) red[wave][rowq + rr] = s[rr];
    }
    __syncthreads();
    float mean[4];
    #pragma unroll
    for (int rr = 0; rr < 4; ++rr) {
        float tot = red[0][rowq + rr] + red[1][rowq + rr] +
                    red[2][rowq + rr] + red[3][rowq + rr];
        mean[rr] = tot * (1.f / 384.f);
    }
    float q2[4] = {0.f, 0.f, 0.f, 0.f};
    #pragma unroll
    for (int ct = 0; ct < 6; ++ct)
        #pragma unroll
        for (int rr = 0; rr < 4; ++rr) {
            float d = v[ct][rr] - mean[rr]; q2[rr] += d * d;
        }
    #pragma unroll
    for (int off = 1; off < 16; off <<= 1)
        #pragma unroll
        for (int rr = 0; rr < 4; ++rr) q2[rr] += __shfl_xor(q2[rr], off);
    __syncthreads();   // red round-1 reads done before overwrite
    if (l15 == 0) {
        #pragma unroll
        for (int rr = 0; rr < 4; ++rr) red[wave][rowq + rr] = q2[rr];
    }
    __syncthreads();
    #pragma unroll
    for (int rr = 0; rr < 4; ++rr) {
        float tot = red[0][rowq + rr] + red[1][rowq + rr] +
                    red[2][rowq + rr] + red[3][rowq + rr];
        float rstd = rsqrtf(tot * (1.f / 384.f) + 1e-5f);
        #pragma unroll
        for (int ct = 0; ct < 6; ++ct) {
            int n = wave * 96 + ct * 16 + colq;
            lnout[(size_t)(m0 + rowq + rr) * 384 + n] =
                f2bf((v[ct][rr] - mean[rr]) * rstd * lw[n] + lb[n]);
        }
    }
}

// ---------------- MFMA bf16 GEMM 64x32: fused residual epilogue (fc2) --------
__global__ __launch_bounds__(256) void mfma_gemm32(
        const u16* __restrict__ A, const u16* __restrict__ Wt,
        const float* __restrict__ bias,
        float* __restrict__ y, int addy, int M, int N, int K)
{
    __shared__ u16 As[2][4096];
    __shared__ u16 Bs[2][2048];
    int t = threadIdx.x;
    int lane = t & 63, wave = t >> 6;
    int wm = (wave >> 1) * 32, wn = (wave & 1) * 16;
    int m0 = blockIdx.y * 64, n0 = blockIdx.x * 32;

    int r0 = t >> 2, c0 = ((t & 3) ^ swz(t >> 2)) * 8;
    const u16* a0 = A + (size_t)(m0 + r0) * K + c0;
    int tb = t & 127;
    int rb = tb >> 2, cb = ((tb & 3) ^ swz(tb >> 2)) * 8;
    const u16* b0 = Wt + (size_t)(n0 + rb) * K + cb;

    auto stage = [&](int k0, int buf) {
        ldsload16(a0 + k0,      &As[buf][wave * 512]);
        ldsload16(a0 + k0 + 32, &As[buf][2048 + wave * 512]);
        if (wave < 2) ldsload16(b0 + k0,      &Bs[buf][wave * 512]);
        else          ldsload16(b0 + k0 + 32, &Bs[buf][1024 + (wave - 2) * 512]);
    };

    f32x4 acc[2] = {};
    int row_a = wm + (lane & 15);
    int row_b = wn + (lane & 15);
    int lq = lane >> 4;
    int nchunks = K / 64;

    stage(0, 0);
    __syncthreads();

    for (int ci = 0; ci < nchunks; ++ci) {
        int p = ci & 1;
        bool pref = (ci + 1 < nchunks);
        if (pref) stage((ci + 1) * 64, 1 - p);
        #pragma unroll
        for (int hf = 0; hf < 2; ++hf) {
            bf16x8 af[2], bf0;
            #pragma unroll
            for (int i = 0; i < 2; ++i) {
                int r = row_a + i * 16;
                af[i] = *(const bf16x8*)&As[p][hf * 2048 + r * 32 + ((lq ^ swz(r)) * 8)];
            }
            {
                int r = row_b;
                bf0 = *(const bf16x8*)&Bs[p][hf * 1024 + r * 32 + ((lq ^ swz(r)) * 8)];
            }
            #pragma unroll
            for (int i = 0; i < 2; ++i)
                acc[i] = __builtin_amdgcn_mfma_f32_16x16x32_bf16(
                    af[i], bf0, acc[i], 0, 0, 0);
        }
        if (pref) __syncthreads();
    }

    int colq = lane & 15, rowq = (lane >> 4) * 4;
    #pragma unroll
    for (int i = 0; i < 2; ++i) {
        #pragma unroll
        for (int rr = 0; rr < 4; ++rr) {
            int m = m0 + wm + i * 16 + rowq + rr;
            size_t mo = (size_t)m * N;
            int n = n0 + wn + colq;
            float v = acc[i][rr] + bias[n];
            if (addy) v += y[mo + n];
            y[mo + n] = v;
        }
    }
}

// ---------------- MFMA flash attention ---------------------------------------
// W==32: global, grid (24, 16, 2) -- key-split 2, unnormalized partials out.
// W==14: windowed, grid (216, 4, 1) -- direct bf16 out; kofs LDS bias-index
//        table replaces incremental coords; fully-invalid query waves skip
//        compute (still stage K/V + hit barriers).
template<int N, int W>
__global__ __launch_bounds__(256) void attn_mfma(const u16* __restrict__ qkv,
        const u16* __restrict__ qkb, const float* __restrict__ rh,
        const float* __restrict__ rw, u16* __restrict__ outb,
        float* __restrict__ opart, float* __restrict__ lpart)
{
    constexpr int JS = (W == 32) ? 64 : 32;
    constexpr int L  = (W == 32) ? 63 : 27;
    constexpr int CTR = W - 1;
    constexpr int KSPAN = (W == 32) ? 512 : 224;
    constexpr int NKT = KSPAN / 32;
    __shared__ u16 KV[11776];  // Ks[2][2048] | Vt[2][2560] | Pb[2560]
    __shared__ u16 bhl[64 * 66];
    __shared__ u16 bwl[64 * 66];
    __shared__ u16 Qt[64 * 66];
    __shared__ unsigned kofs[224];   // W==14: (kh | kw<<16) per key

    u16* Pb = KV + 9216;
    u16* Rt = KV;

    int t = threadIdx.x, lane = t & 63, wave = t >> 6;
    int quad = lane >> 4, l15 = lane & 15;
    int uh = blockIdx.x, qb0 = blockIdx.y * 64;
    int z = (W == 32) ? blockIdx.z : 0;
    int kstart = z * KSPAN;
    int h = uh % HEADS, u = uh / HEADS;
    size_t tbase = (size_t)u * 1024;
    int wb_ = u / 9, wr = u - wb_ * 9;
    int wy = wr / 3, wx = wr - wy * 3;

    auto tok14 = [&](int iy, int ix) -> const u16* {
        int gy = wy * WS + iy, gx = wx * WS + ix;
        if (gy < 32 && gx < 32)
            return qkv + (size_t)(wb_ * 1024 + gy * 32 + gx) * 1152;
        return qkb;
    };
    auto rowptr = [&](int lq2) -> const u16* {   // div-based, prologue only
        if constexpr (W == 32) {
            return qkv + (tbase + lq2) * 1152;
        } else {
            int iy = lq2 / WS, ix = lq2 - iy * WS;
            return tok14(iy, ix);
        }
    };

    // ---- stage Q^T (unscaled) ----
    {
        int q = t & 63, ch0 = (t >> 6) * 16;
        int qc = qb0 + q; if (qc >= N) qc = N - 1;
        const u16* qp = rowptr(qc) + h * 64 + ch0;
        uint4 a = *(const uint4*)qp;
        uint4 b = *(const uint4*)(qp + 8);
        u16 vals[16];
        *(uint4*)vals = a; *(uint4*)(vals + 8) = b;
        #pragma unroll
        for (int c = 0; c < 16; ++c)
            Qt[(ch0 + c) * 66 + q] = ((qb0 + q) < N) ? vals[c] : (u16)0;
    }

    // ---- W==14: key -> (kh,kw) LDS table ----
    if constexpr (W != 32) {
        if (t < 224) {
            int kh = t / WS;
            kofs[t] = (unsigned)kh | ((unsigned)(t - kh * WS) << 16);
        }
    }

    // ---- stage BOTH rel-pos tables (bf16) into Rt ----
    for (int idx = t; idx < JS * 16; idx += 256) {
        int table = (idx >= JS * 8) ? 1 : 0;
        int id2 = idx & (JS * 8 - 1);
        int j = id2 >> 3, cc0 = (id2 & 7) * 8;
        const float* tab = table ? rw : rh;
        u16 tmp[8];
        if (j < L) {
            const float* src = tab + (size_t)j * 64 + cc0;
            #pragma unroll
            for (int c = 0; c < 8; ++c) tmp[c] = f2bf(src[c]);
        } else {
            #pragma unroll
            for (int c = 0; c < 8; ++c) tmp[c] = 0;
        }
        *(uint4*)&Rt[table * JS * 72 + j * 72 + cc0] = *(uint4*)tmp;
    }
    __syncthreads();

    // ---- bias-table MFMAs D = Q . R^T (one phase, both tables) ----
    {
        int tb0 = (W == 32) ? 0 : (wave >> 1);
        int ntb = (W == 32) ? 2 : 1;
        int jt  = (W == 32) ? wave : (wave & 1);
        for (int tt = 0; tt < ntb; ++tt) {
            int table = tb0 + tt;
            const u16* Rtt = Rt + table * JS * 72;
            bf16x8 af0 = *(const bf16x8*)&Rtt[(jt * 16 + l15) * 72 + quad * 8];
            bf16x8 af1 = *(const bf16x8*)&Rtt[(jt * 16 + l15) * 72 + 32 + quad * 8];
            u16* dst = table ? bwl : bhl;
            #pragma unroll
            for (int qt = 0; qt < 4; ++qt) {
                bf16x8 qf0, qf1;
                u16* p0 = (u16*)&qf0; u16* p1 = (u16*)&qf1;
                #pragma unroll
                for (int zz = 0; zz < 8; ++zz) {
                    p0[zz] = Qt[(quad * 8 + zz) * 66 + qt * 16 + l15];
                    p1[zz] = Qt[(32 + quad * 8 + zz) * 66 + qt * 16 + l15];
                }
                f32x4 acc = {};
                acc = __builtin_amdgcn_mfma_f32_16x16x32_bf16(af0, qf0, acc, 0, 0, 0);
                acc = __builtin_amdgcn_mfma_f32_16x16x32_bf16(af1, qf1, acc, 0, 0, 0);
                #pragma unroll
                for (int r = 0; r < 4; ++r)
                    dst[(qt * 16 + l15) * 66 + jt * 16 + quad * 4 + r] = f2bf(acc[r]);
            }
        }
    }
    __syncthreads();

    // ---- per-lane staging coordinates (incremental for W==14) ----
    int skey = (wave * 64 + lane) >> 3;             // K-stage key (0..31)
    int sc8  = ((wave * 64 + lane) & 7) ^ (skey & 7);
    int vkey = t & 31, vch0 = (t >> 5) * 8;         // V-stage key/ch
    int siy = 0, six = 0, viy = 0, vix = 0;
    if constexpr (W != 32) {
        int k0 = kstart + skey;   // kstart==0
        siy = k0 / WS; six = k0 - siy * WS;
        int k1 = kstart + vkey;
        viy = k1 / WS; vix = k1 - viy * WS;
    }
    auto adv = [](int& iy, int& ix) { ix += 4; iy += 2; if (ix >= WS) { ix -= WS; ++iy; } };

    // ---- stage tile 0 into buffer 0 ----
    {
        const u16* kp = (W == 32) ? qkv + (tbase + kstart + skey) * 1152
                                  : tok14(siy, six);
        ldsload16(kp + 384 + h * 64 + sc8 * 8, KV + wave * 512);
        const u16* vp = (W == 32) ? qkv + (tbase + kstart + vkey) * 1152
                                  : tok14(viy, vix);
        uint4 vv = *(const uint4*)(vp + 768 + h * 64 + vch0);
        u16 tmp[8]; *(uint4*)tmp = vv;
        u16* vdst = KV + 4096;
        #pragma unroll
        for (int c = 0; c < 8; ++c) vdst[(vch0 + c) * 40 + vkey] = tmp[c];
        if constexpr (W != 32) { adv(siy, six); adv(viy, vix); }
    }

    // Q^T B-frags (loop-invariant; scale applied to scores)
    bf16x8 qf[2];
    #pragma unroll
    for (int hc = 0; hc < 2; ++hc) {
        u16* qv = (u16*)&qf[hc];
        #pragma unroll
        for (int j = 0; j < 8; ++j)
            qv[j] = Qt[(hc * 32 + quad * 8 + j) * 66 + wave * 16 + l15];
    }
    int qme = wave * 16 + l15;
    // wave-uniform: does this wave's 16-query tile contain any valid query?
    bool wactive = (W == 32) ? true : ((qb0 + wave * 16) < N);
    int qq = qb0 + qme; if (qq >= N) qq = N - 1;
    int qh = qq / W, qw = qq - qh * W;
    int qh13 = qh + CTR, qw13 = qw + CTR;
    float bwreg[2][4];
    if constexpr (W == 32) {
        #pragma unroll
        for (int kc2 = 0; kc2 < 2; ++kc2)
            #pragma unroll
            for (int r = 0; r < 4; ++r) {
                int keyl = kc2 * 16 + quad * 4 + r;
                bwreg[kc2][r] = bf2f(bwl[qme * 66 + (qw - keyl + CTR)]);
            }
    }

    f32x4 of[4] = {};
    float lsum = 0.f;
    __syncthreads();   // tile 0 staged (vmcnt drained)

    for (int kt = 0; kt < NKT; ++kt) {
        int kb = kstart + kt * 32;
        int p = kt & 1;
        const u16* ksp = KV + p * 2048;
        const u16* vtp = KV + 4096 + p * 2560;
        bool pref = (kt + 1 < NKT);
        uint4 vpref;
        if (pref) {
            const u16* kp = (W == 32) ? qkv + (tbase + kb + 32 + skey) * 1152
                                      : tok14(siy, six);
            ldsload16(kp + 384 + h * 64 + sc8 * 8, KV + (1 - p) * 2048 + wave * 512);
            const u16* vp = (W == 32) ? qkv + (tbase + kb + 32 + vkey) * 1152
                                      : tok14(viy, vix);
            vpref = *(const uint4*)(vp + 768 + h * 64 + vch0);
            if constexpr (W != 32) { adv(siy, six); adv(viy, vix); }
        }

        // ---- compute tile kt (skipped by fully-invalid query waves) ----
        if (wactive) {
            f32x4 st[2] = {};
            #pragma unroll
            for (int hc = 0; hc < 2; ++hc) {
                #pragma unroll
                for (int kc2 = 0; kc2 < 2; ++kc2) {
                    int key = kc2 * 16 + l15;
                    int c8 = hc * 4 + quad;
                    int pp = key * 8 + (c8 ^ (key & 7));
                    bf16x8 kf = *(const bf16x8*)&ksp[pp * 8];
                    st[kc2] = __builtin_amdgcn_mfma_f32_16x16x32_bf16(
                        kf, qf[hc], st[kc2], 0, 0, 0);
                }
            }
            float bh_t = 0.f;
            if constexpr (W == 32) bh_t = bf2f(bhl[qme * 66 + (qh - (kb >> 5) + CTR)]);
            #pragma unroll
            for (int kc2 = 0; kc2 < 2; ++kc2) {
                float pv4[4];
                #pragma unroll
                for (int r = 0; r < 4; ++r) {
                    int keyl = kc2 * 16 + quad * 4 + r;
                    float pv;
                    if constexpr (W == 32) {
                        float b = bh_t + bwreg[kc2][r];
                        pv = __expf(fmaf(st[kc2][r], 0.125f, b));
                    } else {
                        unsigned ko = kofs[kb + keyl];
                        float b = bf2f(bhl[qme * 66 + qh13 - (int)(ko & 0xffffu)]) +
                                  bf2f(bwl[qme * 66 + qw13 - (int)(ko >> 16)]);
                        pv = __expf(fmaf(st[kc2][r], 0.125f, b));
                        if (kb + keyl >= N) pv = 0.f;
                    }
                    lsum += pv;
                    pv4[r] = pv;
                }
                uint2 pk;
                pk.x = pk2bf(pv4[0], pv4[1]);
                pk.y = pk2bf(pv4[2], pv4[3]);
                *(uint2*)&Pb[wave * 640 + l15 * 40 + kc2 * 16 + quad * 4] = pk;
            }
            bf16x8 pf = *(const bf16x8*)&Pb[wave * 640 + l15 * 40 + quad * 8];
            #pragma unroll
            for (int ca = 0; ca < 4; ++ca) {
                bf16x8 vf = *(const bf16x8*)&vtp[(ca * 16 + l15) * 40 + quad * 8];
                of[ca] = __builtin_amdgcn_mfma_f32_16x16x32_bf16(
                    vf, pf, of[ca], 0, 0, 0);
            }
        }

        if (pref) {
            u16 tmp[8]; *(uint4*)tmp = vpref;
            u16* vdst = KV + 4096 + (1 - p) * 2560;
            #pragma unroll
            for (int c = 0; c < 8; ++c) vdst[(vch0 + c) * 40 + vkey] = tmp[c];
            __syncthreads();
        }
    }

    lsum += __shfl_xor(lsum, 16);
    lsum += __shfl_xor(lsum, 32);
    int q = qb0 + qme;
    if constexpr (W == 32) {
        // unnormalized partials: O fp32 + l
        size_t ridx = (size_t)z * 24576 + (size_t)uh * 1024 + q;
        float* op = opart + ridx * 64;
        #pragma unroll
        for (int ca = 0; ca < 4; ++ca)
            *(float4*)&op[ca * 16 + quad * 4] = (float4){of[ca][0], of[ca][1],
                                                         of[ca][2], of[ca][3]};
        if (quad == 0) lpart[ridx] = lsum;
    } else {
        float inv = 1.f / lsum;
        if (q < N) {
            int iy = q / WS, ix = q - iy * WS;
            int gy = wy * WS + iy, gx = wx * WS + ix;
            if (gy >= 32 || gx >= 32) return;
            u16* op = outb + (size_t)(wb_ * 1024 + gy * 32 + gx) * 384 + h * 64;
            #pragma unroll
            for (int ca = 0; ca < 4; ++ca) {
                uint2 pk;
                pk.x = pk2bf(of[ca][0] * inv, of[ca][1] * inv);
                pk.y = pk2bf(of[ca][2] * inv, of[ca][3] * inv);
                *(uint2*)&op[ca * 16 + quad * 4] = pk;
            }
        }
    }
}

// ---------------- merge split-key attention partials (x4 vectorized) ---------
__global__ __launch_bounds__(256) void attn_merge_kernel(const float* __restrict__ O,
        const float* __restrict__ Lp, u16* __restrict__ attb)
{
    int gi = blockIdx.x * 256 + threadIdx.x;   // 393216 threads, 4 ch each
    int idx = gi >> 4;                          // uh*1024 + q
    int ch = (gi & 15) * 4;
    float4 o0 = *(const float4*)&O[(size_t)idx * 64 + ch];
    float4 o1 = *(const float4*)&O[((size_t)24576 + idx) * 64 + ch];
    float inv = 1.f / (Lp[idx] + Lp[24576 + idx]);
    int uh = idx >> 10, q = idx & 1023;
    int u = uh / 6, h = uh - u * 6;
    uint2 pk;
    pk.x = pk2bf((o0.x + o1.x) * inv, (o0.y + o1.y) * inv);
    pk.y = pk2bf((o0.z + o1.z) * inv, (o0.w + o1.w) * inv);
    *(uint2*)(attb + ((size_t)(u * 1024 + q)) * 384 + h * 64 + ch) = pk;
}

// ---------------- host helpers ----------------
static inline void launch_gemm(const u16* A, const u16* W, const float* bias,
                               u16* outb, int M, int N, int K, int act,
                               hipStream_t s) {
    dim3 g(N / 64, M / 128, 1);
    mfma_gemm4<<<g, 256, 0, s>>>(A, W, bias, outb, M, N, K, act);
}

static inline void launch_gemm64b(const u16* A, const u16* W, const float* bias,
                                  u16* outb, int M, int N, int K, hipStream_t s) {
    dim3 g(N / 64, M / 64, 1);
    mfma_gemm64b<<<g, 256, 0, s>>>(A, W, bias, outb, M, N, K);
}

// full-row fused GEMM + residual + LN: grid M/16 = 256 blocks
static inline void launch_gemm_fr(const u16* A, const u16* W, const float* bias,
                                  const float* posr, float* y, int addy,
                                  const float* lw, const float* lb, u16* lnout,
                                  int M, int K, hipStream_t s) {
    mfma_gemm_fr<<<M / 16, 256, 0, s>>>(A, W, bias, posr, y, addy, lw, lb,
                                        lnout, M, K);
}

static inline void launch_gemm32(const u16* A, const u16* W, const float* bias,
                                 float* y, int addy, int M, int N, int K,
                                 hipStream_t s) {
    dim3 g(N / 32, M / 64, 1);
    mfma_gemm32<<<g, 256, 0, s>>>(A, W, bias, y, addy, M, N, K);
}

extern "C" void kernel_launch(void* const* d_in, const int* in_sizes, int n_in,
                              void* d_out, int out_size, void* d_ws, size_t ws_size,
                              hipStream_t stream) {
    const float* x      = (const float*)d_in[0];
    const float* patchw = (const float*)d_in[1];
    const float* patchb = (const float*)d_in[2];
    const float* pos    = (const float*)d_in[3];
    const float* n1w    = (const float*)d_in[4];
    const float* n1b    = (const float*)d_in[5];
    const float* qkvw   = (const float*)d_in[6];
    const float* qkvb   = (const float*)d_in[7];
    const float* pw     = (const float*)d_in[8];
    const float* pb     = (const float*)d_in[9];
    const float* n2w    = (const float*)d_in[10];
    const float* n2b    = (const float*)d_in[11];
    const float* f1w    = (const float*)d_in[12];
    const float* f1b    = (const float*)d_in[13];
    const float* f2w    = (const float*)d_in[14];
    const float* f2b    = (const float*)d_in[15];
    const float* rph    = (const float*)d_in[16];
    const float* rpw    = (const float*)d_in[17];
    float* out = (float*)d_out;

    // workspace layout (unchanged). Overlays cover only dead buffers:
    //  colb = rsrv (im2col, patch phase only)
    //  Opart = mlpb (global-attn phase), Lpart = lnb (dead post-qkv)
    float* y   = (float*)d_ws;                  // 1,572,864 f32
    u16* attb  = (u16*)(y + 1572864);           // 1,572,864 u16 (token layout)
    u16* mlpb  = attb + 1572864;                // 6,291,456 u16
    u16* lnb   = mlpb + 6291456;                // 1,572,864 u16
    u16* qkvx  = lnb + 1572864;                 // 4,718,592 u16 (4096x1152)
    u16* rsrv  = qkvx + 4718592;                // 7,864,320 u16
    u16* wb    = rsrv + 7864320;                // 10,918,656 u16 (weights + qkv bias)
    float* posr = (float*)(wb + 10918656);      //   393,216 f32

    u16* colb  = rsrv;                          // overlay: im2col 3,145,728 u16
    float* Opart   = (float*)mlpb;              // 2x24576x64 f32 = 12,582,912 B
    float* Lpart   = (float*)lnb;               // 2x24576 f32

    u16* wb_patch = wb;
    u16* wb_qkv   = wb + 294912;
    u16* wb_pw    = wb + 2949120;
    u16* wb_f1    = wb + 3833856;
    u16* wb_f2    = wb + 7372800;
    u16* wqb      = wb + 10911744;              // bf16 qkv bias, 6 x 1152

    setup_kernel<<<(14457600 / 4 + 255) / 256, 256, 0, stream>>>(
        patchw, qkvw, pw, f1w, f2w, qkvb, wb, pos, posr, x, colb);

    // patch embed: full-row GEMM, fused bias + pos-embed + LN(n1) -> y, lnb
    launch_gemm_fr(colb, wb_patch, patchb, posr, y, 0, n1w, n1b, lnb,
                   NTOK, 768, stream);

    for (int i = 0; i < 6; ++i) {
        bool windowed = (i == 0 || i == 1 || i == 3 || i == 4);
        const float* rh = rph + (size_t)i * 63 * 64;
        const float* rw = rpw + (size_t)i * 63 * 64;
        launch_gemm64b(lnb, wb_qkv + (size_t)i * 442368, qkvb + i * 1152,
                       qkvx, NTOK, 1152, 384, stream);
        if (windowed) {
            attn_mfma<WTOK, WS><<<dim3(NWIN * HEADS, 4, 1), 256, 0, stream>>>(
                qkvx, wqb + i * 1152, rh, rw, attb, nullptr, nullptr);
        } else {
            attn_mfma<1024, 32><<<dim3(B_SZ * HEADS, 16, 2), 256, 0, stream>>>(
                qkvx, wqb + i * 1152, rh, rw, nullptr, Opart, Lpart);
            attn_merge_kernel<<<1536, 256, 0, stream>>>(Opart, Lpart, attb);
        }
        // proj: full-row GEMM, fused bias + residual + LN(n2) -> y, lnb
        launch_gemm_fr(attb, wb_pw + (size_t)i * 147456, pb + i * 384,
                       nullptr, y, 1, n2w + i * 384, n2b + i * 384, lnb,
                       NTOK, 384, stream);
        launch_gemm(lnb, wb_f1 + (size_t)i * 589824, f1b + i * 1536,
                    mlpb, NTOK, 1536, 384, 1, stream);
        // fc2: fused bias + residual accumulate onto y
        launch_gemm32(mlpb, wb_f2 + (size_t)i * 589824, f2b + i * 384,
                      y, 1, NTOK, 384, 1536, stream);
        if (i < 5)
            ln_kernel<<<1024, 256, 0, stream>>>(y, n1w + (i + 1) * 384,
                                                n1b + (i + 1) * 384, lnb);
        else
            out_transpose<<<dim3(6, 64), 256, 0, stream>>>(y, out);
    }
}

// Round 7
// 684.132 us; speedup vs baseline: 1.0388x; 1.0388x over previous
//
#include <hip/hip_runtime.h>
#include <hip/hip_bf16.h>
#include <math.h>

// ---------------- constants ----------------
#define B_SZ 4
#define DIM 384
#define HEADS 6
#define HD 64
#define NTOK 4096          // B*32*32
#define WS 14
#define NWIN 36            // B * 9
#define WTOK 196           // 14*14

typedef unsigned short u16;
typedef __bf16 bf16_t;
typedef bf16_t bf16x8 __attribute__((ext_vector_type(8)));
typedef float f32x4 __attribute__((ext_vector_type(4)));

__device__ __forceinline__ float bf2f(unsigned u) { return __uint_as_float(u << 16); }
__device__ __forceinline__ u16 f2bf(float f) {
    unsigned u = __float_as_uint(f);
    unsigned r = (u + 0x7fffu + ((u >> 16) & 1u)) >> 16;
    return (u16)r;
}
// packed RNE f32x2 -> bf16x2 (hardware v_cvt_pk_bf16_f32 on gfx950)
__device__ __forceinline__ unsigned pk2bf(float a, float b) {
    __hip_bfloat162 h = __float22bfloat162_rn(make_float2(a, b));
    unsigned r; __builtin_memcpy(&r, &h, 4); return r;
}

// async global->LDS, 16B per lane, wave-uniform LDS base + lane*16
__device__ __forceinline__ void ldsload16(const u16* g, u16* l) {
    __builtin_amdgcn_global_load_lds(
        (const __attribute__((address_space(1))) unsigned int*)g,
        (__attribute__((address_space(3))) unsigned int*)l, 16, 0, 0);
}

__device__ __forceinline__ int swz(int r) { return (r ^ (r >> 2)) & 3; }

// ---------------- bicubic helper ----------------
__device__ inline float cubic_keys(float x) {
    x = fabsf(x);
    if (x <= 1.f) return ((1.5f * x - 2.5f) * x) * x + 1.f;
    if (x < 2.f)  return ((-0.5f * x + 2.5f) * x - 4.f) * x + 2.f;
    return 0.f;
}

// ---------------- one-shot setup (x4 vectorized) -----------------------------
__global__ __launch_bounds__(256) void setup_kernel(
        const float* __restrict__ p0, const float* __restrict__ p1,
        const float* __restrict__ p2, const float* __restrict__ p3,
        const float* __restrict__ p4, const float* __restrict__ p5,
        u16* __restrict__ wb, const float* __restrict__ pe,
        float* __restrict__ posr, const float* __restrict__ x,
        u16* __restrict__ col) {
    int i = (blockIdx.x * 256 + threadIdx.x) * 4;
    if (i < 10918656) {
        const float* s; int off;
        if      (i <   294912) { s = p0; off = 0; }
        else if (i <  2949120) { s = p1; off = 294912; }
        else if (i <  3833856) { s = p2; off = 2949120; }
        else if (i <  7372800) { s = p3; off = 3833856; }
        else if (i < 10911744) { s = p4; off = 7372800; }
        else                   { s = p5; off = 10911744; }
        float4 v = *(const float4*)(s + (i - off));
        u16 o[4] = { f2bf(v.x), f2bf(v.y), f2bf(v.z), f2bf(v.w) };
        *(uint2*)(wb + i) = *(const uint2*)o;
        return;
    }
    i -= 10918656;
    if (i < 393216) {
        int c = i % 384;
        int g = i / 384;
        int gy = g / 32, gx = g % 32;
        float wy[14], wx[14];
        float sy = (gy + 0.5f) * (14.f / 32.f) - 0.5f;
        float sx = (gx + 0.5f) * (14.f / 32.f) - 0.5f;
        float toty = 0.f, totx = 0.f;
        #pragma unroll
        for (int k = 0; k < 14; ++k) {
            wy[k] = cubic_keys(sy - (float)k); toty += wy[k];
            wx[k] = cubic_keys(sx - (float)k); totx += wx[k];
        }
        float4 acc = {0.f, 0.f, 0.f, 0.f};
        #pragma unroll 1
        for (int iy = 0; iy < 14; ++iy) {
            if (wy[iy] == 0.f) continue;
            float4 row = {0.f, 0.f, 0.f, 0.f};
            for (int ix = 0; ix < 14; ++ix) {
                if (wx[ix] == 0.f) continue;
                float4 pv = *(const float4*)(pe + (iy * 14 + ix) * 384 + c);
                row.x += wx[ix] * pv.x; row.y += wx[ix] * pv.y;
                row.z += wx[ix] * pv.z; row.w += wx[ix] * pv.w;
            }
            acc.x += wy[iy] * row.x; acc.y += wy[iy] * row.y;
            acc.z += wy[iy] * row.z; acc.w += wy[iy] * row.w;
        }
        float inv = 1.f / (toty * totx);
        acc.x *= inv; acc.y *= inv; acc.z *= inv; acc.w *= inv;
        *(float4*)(posr + i) = acc;
        return;
    }
    i -= 393216;
    if (i < 3145728) {
        int kk = i % 768;
        int p  = i / 768;
        int b  = p / 1024;
        int ph = (p % 1024) / 32;
        int pw = p % 32;
        int c = kk / 256;
        int r = kk % 256;
        int ii = r / 16, j = r % 16;
        float4 v = *(const float4*)(x + (size_t)b * 3 * 512 * 512 +
                                    (size_t)c * 512 * 512 +
                                    (size_t)(ph * 16 + ii) * 512 + (pw * 16 + j));
        u16 o[4] = { f2bf(v.x), f2bf(v.y), f2bf(v.z), f2bf(v.w) };
        *(uint2*)(col + i) = *(const uint2*)o;
    }
}

// ---------------- slim LN kernel: y (f32) -> lnb (bf16) ----------------------
// 256 threads = 4 tokens/block (1 wave per token)
__global__ __launch_bounds__(256) void ln_kernel(const float* __restrict__ y,
        const float* __restrict__ lw, const float* __restrict__ lb,
        u16* __restrict__ lnout)
{
    int tok = blockIdx.x * 4 + (threadIdx.x >> 6);
    int t = threadIdx.x & 63;
    size_t base = (size_t)tok * 384;
    float v[6];
    float s = 0.f;
    #pragma unroll
    for (int i = 0; i < 6; ++i) {
        v[i] = y[base + t + 64 * i]; s += v[i];
    }
    #pragma unroll
    for (int off = 32; off > 0; off >>= 1) s += __shfl_xor(s, off);
    float mean = s * (1.f / 384.f);
    float vs = 0.f;
    #pragma unroll
    for (int i = 0; i < 6; ++i) { float d = v[i] - mean; vs += d * d; }
    #pragma unroll
    for (int off = 32; off > 0; off >>= 1) vs += __shfl_xor(vs, off);
    float inv = rsqrtf(vs * (1.f / 384.f) + 1e-5f);
    u16* orow = lnout + base;
    #pragma unroll
    for (int i = 0; i < 6; ++i) {
        int c = t + 64 * i;
        orow[c] = f2bf((v[i] - mean) * inv * lw[c] + lb[c]);
    }
}

// ---------------- coalesced NHWC(f32 y) -> NCHW out via LDS transpose --------
__global__ __launch_bounds__(256) void out_transpose(const float* __restrict__ y,
        float* __restrict__ outT)
{
    __shared__ float T[64][65];
    int c0 = blockIdx.x * 64, m0 = blockIdx.y * 64;
    int t = threadIdx.x;
    int cl = t & 63, wv = t >> 6;
    #pragma unroll
    for (int r = 0; r < 16; ++r) {
        int ml = wv * 16 + r;
        T[ml][cl] = y[(size_t)(m0 + ml) * 384 + c0 + cl];
    }
    __syncthreads();
    int b = m0 >> 10, g0 = m0 & 1023;
    int gl = t & 63;
    #pragma unroll
    for (int r = 0; r < 16; ++r) {
        int ccl = wv * 16 + r;
        outT[((size_t)(b * 384 + c0 + ccl)) * 1024 + g0 + gl] = T[gl][ccl];
    }
}

// ---------------- MFMA bf16 GEMM v4: BM=128, BN=64, BK=64, dbuf --------------
// used for fc1 (GELU, bf16 out); grid (24,32)=768 = 3/CU exact
__global__ __launch_bounds__(256) void mfma_gemm4(
        const u16* __restrict__ A, const u16* __restrict__ Wt,
        const float* __restrict__ bias,
        u16* __restrict__ outb,
        int M, int N, int K, int act)
{
    __shared__ u16 As[2][8192];
    __shared__ u16 Bs[2][4096];
    int t = threadIdx.x;
    int lane = t & 63, wave = t >> 6;
    int wm = (wave >> 1) * 64, wn = (wave & 1) * 32;
    int m0 = blockIdx.y * 128, n0 = blockIdx.x * 64;

    int r0 = t >> 2,        c0 = ((t & 3) ^ swz(t >> 2)) * 8;
    int r1 = 64 + (t >> 2), c1 = ((t & 3) ^ swz(64 + (t >> 2))) * 8;
    const u16* a0 = A + (size_t)(m0 + r0) * K + c0;
    const u16* a1 = A + (size_t)(m0 + r1) * K + c1;
    const u16* b0 = Wt + (size_t)(n0 + r0) * K + c0;

    auto stage = [&](int k0, int buf) {
        ldsload16(a0 + k0,      &As[buf][wave * 512]);
        ldsload16(a1 + k0,      &As[buf][2048 + wave * 512]);
        ldsload16(b0 + k0,      &Bs[buf][wave * 512]);
        ldsload16(a0 + k0 + 32, &As[buf][4096 + wave * 512]);
        ldsload16(a1 + k0 + 32, &As[buf][6144 + wave * 512]);
        ldsload16(b0 + k0 + 32, &Bs[buf][2048 + wave * 512]);
    };

    f32x4 acc[4][2] = {};
    int row_a = wm + (lane & 15);
    int row_b = wn + (lane & 15);
    int lq = lane >> 4;
    int nchunks = K / 64;

    stage(0, 0);
    __syncthreads();

    for (int ci = 0; ci < nchunks; ++ci) {
        int p = ci & 1;
        bool pref = (ci + 1 < nchunks);
        if (pref) stage((ci + 1) * 64, 1 - p);
        #pragma unroll
        for (int hf = 0; hf < 2; ++hf) {
            bf16x8 af[4], bfr[2];
            #pragma unroll
            for (int i = 0; i < 4; ++i) {
                int r = row_a + i * 16;
                af[i] = *(const bf16x8*)&As[p][hf * 4096 + r * 32 + ((lq ^ swz(r)) * 8)];
            }
            #pragma unroll
            for (int j = 0; j < 2; ++j) {
                int r = row_b + j * 16;
                bfr[j] = *(const bf16x8*)&Bs[p][hf * 2048 + r * 32 + ((lq ^ swz(r)) * 8)];
            }
            #pragma unroll
            for (int i = 0; i < 4; ++i)
                #pragma unroll
                for (int j = 0; j < 2; ++j)
                    acc[i][j] = __builtin_amdgcn_mfma_f32_16x16x32_bf16(
                        af[i], bfr[j], acc[i][j], 0, 0, 0);
        }
        if (pref) __syncthreads();
    }

    int colq = lane & 15, rowq = (lane >> 4) * 4;
    #pragma unroll
    for (int i = 0; i < 4; ++i) {
        #pragma unroll
        for (int rr = 0; rr < 4; ++rr) {
            int m = m0 + wm + i * 16 + rowq + rr;
            size_t mo = (size_t)m * N;
            #pragma unroll
            for (int j = 0; j < 2; ++j) {
                int n = n0 + wn + j * 16 + colq;
                float v = acc[i][j][rr] + bias[n];
                if (act)  v = 0.5f * v * (1.f + erff(v * 0.70710678118654752f));
                outb[mo + n] = f2bf(v);
            }
        }
    }
}

// ---------------- MFMA bf16 GEMM 64x32: fused residual epilogue --------------
// N=384: grid (12, M/64) = 768 blocks = 3/CU exactly (balanced).
__global__ __launch_bounds__(256) void mfma_gemm32(
        const u16* __restrict__ A, const u16* __restrict__ Wt,
        const float* __restrict__ bias, const float* __restrict__ posr,
        float* __restrict__ y, int addy, int M, int N, int K)
{
    __shared__ u16 As[2][4096];
    __shared__ u16 Bs[2][2048];
    int t = threadIdx.x;
    int lane = t & 63, wave = t >> 6;
    int wm = (wave >> 1) * 32, wn = (wave & 1) * 16;
    int m0 = blockIdx.y * 64, n0 = blockIdx.x * 32;

    int r0 = t >> 2, c0 = ((t & 3) ^ swz(t >> 2)) * 8;
    const u16* a0 = A + (size_t)(m0 + r0) * K + c0;
    int tb = t & 127;
    int rb = tb >> 2, cb = ((tb & 3) ^ swz(tb >> 2)) * 8;
    const u16* b0 = Wt + (size_t)(n0 + rb) * K + cb;

    auto stage = [&](int k0, int buf) {
        ldsload16(a0 + k0,      &As[buf][wave * 512]);
        ldsload16(a0 + k0 + 32, &As[buf][2048 + wave * 512]);
        if (wave < 2) ldsload16(b0 + k0,      &Bs[buf][wave * 512]);
        else          ldsload16(b0 + k0 + 32, &Bs[buf][1024 + (wave - 2) * 512]);
    };

    f32x4 acc[2] = {};
    int row_a = wm + (lane & 15);
    int row_b = wn + (lane & 15);
    int lq = lane >> 4;
    int nchunks = K / 64;

    stage(0, 0);
    __syncthreads();

    for (int ci = 0; ci < nchunks; ++ci) {
        int p = ci & 1;
        bool pref = (ci + 1 < nchunks);
        if (pref) stage((ci + 1) * 64, 1 - p);
        #pragma unroll
        for (int hf = 0; hf < 2; ++hf) {
            bf16x8 af[2], bf0;
            #pragma unroll
            for (int i = 0; i < 2; ++i) {
                int r = row_a + i * 16;
                af[i] = *(const bf16x8*)&As[p][hf * 2048 + r * 32 + ((lq ^ swz(r)) * 8)];
            }
            {
                int r = row_b;
                bf0 = *(const bf16x8*)&Bs[p][hf * 1024 + r * 32 + ((lq ^ swz(r)) * 8)];
            }
            #pragma unroll
            for (int i = 0; i < 2; ++i)
                acc[i] = __builtin_amdgcn_mfma_f32_16x16x32_bf16(
                    af[i], bf0, acc[i], 0, 0, 0);
        }
        if (pref) __syncthreads();
    }

    int colq = lane & 15, rowq = (lane >> 4) * 4;
    #pragma unroll
    for (int i = 0; i < 2; ++i) {
        #pragma unroll
        for (int rr = 0; rr < 4; ++rr) {
            int m = m0 + wm + i * 16 + rowq + rr;
            size_t mo = (size_t)m * N;
            int n = n0 + wn + colq;
            float v = acc[i][rr] + bias[n];
            if (posr) v += posr[(size_t)(m & 1023) * 384 + n];
            if (addy) v += y[mo + n];
            y[mo + n] = v;
        }
    }
}

// ---------------- MFMA bf16 GEMM 64x32, bf16+bias out: used for qkv ----------
// same staging/compute skeleton as mfma_gemm32; grid (1152/32, 4096/64) =
// (36, 64) = 2304 blocks = exactly 9/CU (perfectly balanced, 24KB LDS).
__global__ __launch_bounds__(256) void mfma_gemm32b(
        const u16* __restrict__ A, const u16* __restrict__ Wt,
        const float* __restrict__ bias, u16* __restrict__ outb,
        int M, int N, int K)
{
    __shared__ u16 As[2][4096];
    __shared__ u16 Bs[2][2048];
    int t = threadIdx.x;
    int lane = t & 63, wave = t >> 6;
    int wm = (wave >> 1) * 32, wn = (wave & 1) * 16;
    int m0 = blockIdx.y * 64, n0 = blockIdx.x * 32;

    int r0 = t >> 2, c0 = ((t & 3) ^ swz(t >> 2)) * 8;
    const u16* a0 = A + (size_t)(m0 + r0) * K + c0;
    int tb = t & 127;
    int rb = tb >> 2, cb = ((tb & 3) ^ swz(tb >> 2)) * 8;
    const u16* b0 = Wt + (size_t)(n0 + rb) * K + cb;

    auto stage = [&](int k0, int buf) {
        ldsload16(a0 + k0,      &As[buf][wave * 512]);
        ldsload16(a0 + k0 + 32, &As[buf][2048 + wave * 512]);
        if (wave < 2) ldsload16(b0 + k0,      &Bs[buf][wave * 512]);
        else          ldsload16(b0 + k0 + 32, &Bs[buf][1024 + (wave - 2) * 512]);
    };

    f32x4 acc[2] = {};
    int row_a = wm + (lane & 15);
    int row_b = wn + (lane & 15);
    int lq = lane >> 4;
    int nchunks = K / 64;

    stage(0, 0);
    __syncthreads();

    for (int ci = 0; ci < nchunks; ++ci) {
        int p = ci & 1;
        bool pref = (ci + 1 < nchunks);
        if (pref) stage((ci + 1) * 64, 1 - p);
        #pragma unroll
        for (int hf = 0; hf < 2; ++hf) {
            bf16x8 af[2], bf0;
            #pragma unroll
            for (int i = 0; i < 2; ++i) {
                int r = row_a + i * 16;
                af[i] = *(const bf16x8*)&As[p][hf * 2048 + r * 32 + ((lq ^ swz(r)) * 8)];
            }
            {
                int r = row_b;
                bf0 = *(const bf16x8*)&Bs[p][hf * 1024 + r * 32 + ((lq ^ swz(r)) * 8)];
            }
            #pragma unroll
            for (int i = 0; i < 2; ++i)
                acc[i] = __builtin_amdgcn_mfma_f32_16x16x32_bf16(
                    af[i], bf0, acc[i], 0, 0, 0);
        }
        if (pref) __syncthreads();
    }

    int colq = lane & 15, rowq = (lane >> 4) * 4;
    #pragma unroll
    for (int i = 0; i < 2; ++i) {
        #pragma unroll
        for (int rr = 0; rr < 4; ++rr) {
            int m = m0 + wm + i * 16 + rowq + rr;
            size_t mo = (size_t)m * N;
            int n = n0 + wn + colq;
            outb[mo + n] = f2bf(acc[i][rr] + bias[n]);
        }
    }
}

// ---------------- MFMA flash attention ---------------------------------------
// W==32: global, grid (24, 16, 2) -- key-split 2, unnormalized partials out.
// W==14: windowed, grid (216, 4, 1) -- direct bf16 out; kofs LDS bias-index
//        table replaces incremental coords; fully-invalid query waves skip
//        compute (still stage K/V + hit barriers).
template<int N, int W>
__global__ __launch_bounds__(256) void attn_mfma(const u16* __restrict__ qkv,
        const u16* __restrict__ qkb, const float* __restrict__ rh,
        const float* __restrict__ rw, u16* __restrict__ outb,
        float* __restrict__ opart, float* __restrict__ lpart)
{
    constexpr int JS = (W == 32) ? 64 : 32;
    constexpr int L  = (W == 32) ? 63 : 27;
    constexpr int CTR = W - 1;
    constexpr int KSPAN = (W == 32) ? 512 : 224;
    constexpr int NKT = KSPAN / 32;
    __shared__ u16 KV[11776];  // Ks[2][2048] | Vt[2][2560] | Pb[2560]
    __shared__ u16 bhl[64 * 66];
    __shared__ u16 bwl[64 * 66];
    __shared__ u16 Qt[64 * 66];
    __shared__ unsigned kofs[224];   // W==14: (kh | kw<<16) per key

    u16* Pb = KV + 9216;
    u16* Rt = KV;

    int t = threadIdx.x, lane = t & 63, wave = t >> 6;
    int quad = lane >> 4, l15 = lane & 15;
    int uh = blockIdx.x, qb0 = blockIdx.y * 64;
    int z = (W == 32) ? blockIdx.z : 0;
    int kstart = z * KSPAN;
    int h = uh % HEADS, u = uh / HEADS;
    size_t tbase = (size_t)u * 1024;
    int wb_ = u / 9, wr = u - wb_ * 9;
    int wy = wr / 3, wx = wr - wy * 3;

    auto tok14 = [&](int iy, int ix) -> const u16* {
        int gy = wy * WS + iy, gx = wx * WS + ix;
        if (gy < 32 && gx < 32)
            return qkv + (size_t)(wb_ * 1024 + gy * 32 + gx) * 1152;
        return qkb;
    };
    auto rowptr = [&](int lq2) -> const u16* {   // div-based, prologue only
        if constexpr (W == 32) {
            return qkv + (tbase + lq2) * 1152;
        } else {
            int iy = lq2 / WS, ix = lq2 - iy * WS;
            return tok14(iy, ix);
        }
    };

    // ---- stage Q^T (unscaled) ----
    {
        int q = t & 63, ch0 = (t >> 6) * 16;
        int qc = qb0 + q; if (qc >= N) qc = N - 1;
        const u16* qp = rowptr(qc) + h * 64 + ch0;
        uint4 a = *(const uint4*)qp;
        uint4 b = *(const uint4*)(qp + 8);
        u16 vals[16];
        *(uint4*)vals = a; *(uint4*)(vals + 8) = b;
        #pragma unroll
        for (int c = 0; c < 16; ++c)
            Qt[(ch0 + c) * 66 + q] = ((qb0 + q) < N) ? vals[c] : (u16)0;
    }

    // ---- W==14: key -> (kh,kw) LDS table ----
    if constexpr (W != 32) {
        if (t < 224) {
            int kh = t / WS;
            kofs[t] = (unsigned)kh | ((unsigned)(t - kh * WS) << 16);
        }
    }

    // ---- stage BOTH rel-pos tables (bf16) into Rt ----
    for (int idx = t; idx < JS * 16; idx += 256) {
        int table = (idx >= JS * 8) ? 1 : 0;
        int id2 = idx & (JS * 8 - 1);
        int j = id2 >> 3, cc0 = (id2 & 7) * 8;
        const float* tab = table ? rw : rh;
        u16 tmp[8];
        if (j < L) {
            const float* src = tab + (size_t)j * 64 + cc0;
            #pragma unroll
            for (int c = 0; c < 8; ++c) tmp[c] = f2bf(src[c]);
        } else {
            #pragma unroll
            for (int c = 0; c < 8; ++c) tmp[c] = 0;
        }
        *(uint4*)&Rt[table * JS * 72 + j * 72 + cc0] = *(uint4*)tmp;
    }
    __syncthreads();

    // ---- bias-table MFMAs D = Q . R^T (one phase, both tables) ----
    {
        int tb0 = (W == 32) ? 0 : (wave >> 1);
        int ntb = (W == 32) ? 2 : 1;
        int jt  = (W == 32) ? wave : (wave & 1);
        for (int tt = 0; tt < ntb; ++tt) {
            int table = tb0 + tt;
            const u16* Rtt = Rt + table * JS * 72;
            bf16x8 af0 = *(const bf16x8*)&Rtt[(jt * 16 + l15) * 72 + quad * 8];
            bf16x8 af1 = *(const bf16x8*)&Rtt[(jt * 16 + l15) * 72 + 32 + quad * 8];
            u16* dst = table ? bwl : bhl;
            #pragma unroll
            for (int qt = 0; qt < 4; ++qt) {
                bf16x8 qf0, qf1;
                u16* p0 = (u16*)&qf0; u16* p1 = (u16*)&qf1;
                #pragma unroll
                for (int zz = 0; zz < 8; ++zz) {
                    p0[zz] = Qt[(quad * 8 + zz) * 66 + qt * 16 + l15];
                    p1[zz] = Qt[(32 + quad * 8 + zz) * 66 + qt * 16 + l15];
                }
                f32x4 acc = {};
                acc = __builtin_amdgcn_mfma_f32_16x16x32_bf16(af0, qf0, acc, 0, 0, 0);
                acc = __builtin_amdgcn_mfma_f32_16x16x32_bf16(af1, qf1, acc, 0, 0, 0);
                #pragma unroll
                for (int r = 0; r < 4; ++r)
                    dst[(qt * 16 + l15) * 66 + jt * 16 + quad * 4 + r] = f2bf(acc[r]);
            }
        }
    }
    __syncthreads();

    // ---- per-lane staging coordinates (incremental for W==14) ----
    int skey = (wave * 64 + lane) >> 3;             // K-stage key (0..31)
    int sc8  = ((wave * 64 + lane) & 7) ^ (skey & 7);
    int vkey = t & 31, vch0 = (t >> 5) * 8;         // V-stage key/ch
    int siy = 0, six = 0, viy = 0, vix = 0;
    if constexpr (W != 32) {
        int k0 = kstart + skey;   // kstart==0
        siy = k0 / WS; six = k0 - siy * WS;
        int k1 = kstart + vkey;
        viy = k1 / WS; vix = k1 - viy * WS;
    }
    auto adv = [](int& iy, int& ix) { ix += 4; iy += 2; if (ix >= WS) { ix -= WS; ++iy; } };

    // ---- stage tile 0 into buffer 0 ----
    {
        const u16* kp = (W == 32) ? qkv + (tbase + kstart + skey) * 1152
                                  : tok14(siy, six);
        ldsload16(kp + 384 + h * 64 + sc8 * 8, KV + wave * 512);
        const u16* vp = (W == 32) ? qkv + (tbase + kstart + vkey) * 1152
                                  : tok14(viy, vix);
        uint4 vv = *(const uint4*)(vp + 768 + h * 64 + vch0);
        u16 tmp[8]; *(uint4*)tmp = vv;
        u16* vdst = KV + 4096;
        #pragma unroll
        for (int c = 0; c < 8; ++c) vdst[(vch0 + c) * 40 + vkey] = tmp[c];
        if constexpr (W != 32) { adv(siy, six); adv(viy, vix); }
    }

    // Q^T B-frags (loop-invariant; scale applied to scores)
    bf16x8 qf[2];
    #pragma unroll
    for (int hc = 0; hc < 2; ++hc) {
        u16* qv = (u16*)&qf[hc];
        #pragma unroll
        for (int j = 0; j < 8; ++j)
            qv[j] = Qt[(hc * 32 + quad * 8 + j) * 66 + wave * 16 + l15];
    }
    int qme = wave * 16 + l15;
    // wave-uniform: does this wave's 16-query tile contain any valid query?
    bool wactive = (W == 32) ? true : ((qb0 + wave * 16) < N);
    int qq = qb0 + qme; if (qq >= N) qq = N - 1;
    int qh = qq / W, qw = qq - qh * W;
    int qh13 = qh + CTR, qw13 = qw + CTR;
    float bwreg[2][4];
    if constexpr (W == 32) {
        #pragma unroll
        for (int kc2 = 0; kc2 < 2; ++kc2)
            #pragma unroll
            for (int r = 0; r < 4; ++r) {
                int keyl = kc2 * 16 + quad * 4 + r;
                bwreg[kc2][r] = bf2f(bwl[qme * 66 + (qw - keyl + CTR)]);
            }
    }

    f32x4 of[4] = {};
    float lsum = 0.f;
    __syncthreads();   // tile 0 staged (vmcnt drained)

    for (int kt = 0; kt < NKT; ++kt) {
        int kb = kstart + kt * 32;
        int p = kt & 1;
        const u16* ksp = KV + p * 2048;
        const u16* vtp = KV + 4096 + p * 2560;
        bool pref = (kt + 1 < NKT);
        uint4 vpref;
        if (pref) {
            const u16* kp = (W == 32) ? qkv + (tbase + kb + 32 + skey) * 1152
                                      : tok14(siy, six);
            ldsload16(kp + 384 + h * 64 + sc8 * 8, KV + (1 - p) * 2048 + wave * 512);
            const u16* vp = (W == 32) ? qkv + (tbase + kb + 32 + vkey) * 1152
                                      : tok14(viy, vix);
            vpref = *(const uint4*)(vp + 768 + h * 64 + vch0);
            if constexpr (W != 32) { adv(siy, six); adv(viy, vix); }
        }

        // ---- compute tile kt (skipped by fully-invalid query waves) ----
        if (wactive) {
            f32x4 st[2] = {};
            #pragma unroll
            for (int hc = 0; hc < 2; ++hc) {
                #pragma unroll
                for (int kc2 = 0; kc2 < 2; ++kc2) {
                    int key = kc2 * 16 + l15;
                    int c8 = hc * 4 + quad;
                    int pp = key * 8 + (c8 ^ (key & 7));
                    bf16x8 kf = *(const bf16x8*)&ksp[pp * 8];
                    st[kc2] = __builtin_amdgcn_mfma_f32_16x16x32_bf16(
                        kf, qf[hc], st[kc2], 0, 0, 0);
                }
            }
            float bh_t = 0.f;
            if constexpr (W == 32) bh_t = bf2f(bhl[qme * 66 + (qh - (kb >> 5) + CTR)]);
            #pragma unroll
            for (int kc2 = 0; kc2 < 2; ++kc2) {
                float pv4[4];
                #pragma unroll
                for (int r = 0; r < 4; ++r) {
                    int keyl = kc2 * 16 + quad * 4 + r;
                    float pv;
                    if constexpr (W == 32) {
                        float b = bh_t + bwreg[kc2][r];
                        pv = __expf(fmaf(st[kc2][r], 0.125f, b));
                    } else {
                        unsigned ko = kofs[kb + keyl];
                        float b = bf2f(bhl[qme * 66 + qh13 - (int)(ko & 0xffffu)]) +
                                  bf2f(bwl[qme * 66 + qw13 - (int)(ko >> 16)]);
                        pv = __expf(fmaf(st[kc2][r], 0.125f, b));
                        if (kb + keyl >= N) pv = 0.f;
                    }
                    lsum += pv;
                    pv4[r] = pv;
                }
                uint2 pk;
                pk.x = pk2bf(pv4[0], pv4[1]);
                pk.y = pk2bf(pv4[2], pv4[3]);
                *(uint2*)&Pb[wave * 640 + l15 * 40 + kc2 * 16 + quad * 4] = pk;
            }
            bf16x8 pf = *(const bf16x8*)&Pb[wave * 640 + l15 * 40 + quad * 8];
            #pragma unroll
            for (int ca = 0; ca < 4; ++ca) {
                bf16x8 vf = *(const bf16x8*)&vtp[(ca * 16 + l15) * 40 + quad * 8];
                of[ca] = __builtin_amdgcn_mfma_f32_16x16x32_bf16(
                    vf, pf, of[ca], 0, 0, 0);
            }
        }

        if (pref) {
            u16 tmp[8]; *(uint4*)tmp = vpref;
            u16* vdst = KV + 4096 + (1 - p) * 2560;
            #pragma unroll
            for (int c = 0; c < 8; ++c) vdst[(vch0 + c) * 40 + vkey] = tmp[c];
            __syncthreads();
        }
    }

    lsum += __shfl_xor(lsum, 16);
    lsum += __shfl_xor(lsum, 32);
    int q = qb0 + qme;
    if constexpr (W == 32) {
        // unnormalized partials: O fp32 + l
        size_t ridx = (size_t)z * 24576 + (size_t)uh * 1024 + q;
        float* op = opart + ridx * 64;
        #pragma unroll
        for (int ca = 0; ca < 4; ++ca)
            *(float4*)&op[ca * 16 + quad * 4] = (float4){of[ca][0], of[ca][1],
                                                         of[ca][2], of[ca][3]};
        if (quad == 0) lpart[ridx] = lsum;
    } else {
        float inv = 1.f / lsum;
        if (q < N) {
            int iy = q / WS, ix = q - iy * WS;
            int gy = wy * WS + iy, gx = wx * WS + ix;
            if (gy >= 32 || gx >= 32) return;
            u16* op = outb + (size_t)(wb_ * 1024 + gy * 32 + gx) * 384 + h * 64;
            #pragma unroll
            for (int ca = 0; ca < 4; ++ca) {
                uint2 pk;
                pk.x = pk2bf(of[ca][0] * inv, of[ca][1] * inv);
                pk.y = pk2bf(of[ca][2] * inv, of[ca][3] * inv);
                *(uint2*)&op[ca * 16 + quad * 4] = pk;
            }
        }
    }
}

// ---------------- merge split-key attention partials (x4 vectorized) ---------
__global__ __launch_bounds__(256) void attn_merge_kernel(const float* __restrict__ O,
        const float* __restrict__ Lp, u16* __restrict__ attb)
{
    int gi = blockIdx.x * 256 + threadIdx.x;   // 393216 threads, 4 ch each
    int idx = gi >> 4;                          // uh*1024 + q
    int ch = (gi & 15) * 4;
    float4 o0 = *(const float4*)&O[(size_t)idx * 64 + ch];
    float4 o1 = *(const float4*)&O[((size_t)24576 + idx) * 64 + ch];
    float inv = 1.f / (Lp[idx] + Lp[24576 + idx]);
    int uh = idx >> 10, q = idx & 1023;
    int u = uh / 6, h = uh - u * 6;
    uint2 pk;
    pk.x = pk2bf((o0.x + o1.x) * inv, (o0.y + o1.y) * inv);
    pk.y = pk2bf((o0.z + o1.z) * inv, (o0.w + o1.w) * inv);
    *(uint2*)(attb + ((size_t)(u * 1024 + q)) * 384 + h * 64 + ch) = pk;
}

// ---------------- host helpers ----------------
static inline void launch_gemm(const u16* A, const u16* W, const float* bias,
                               u16* outb, int M, int N, int K, int act,
                               hipStream_t s) {
    dim3 g(N / 64, M / 128, 1);
    mfma_gemm4<<<g, 256, 0, s>>>(A, W, bias, outb, M, N, K, act);
}

// BM=64/BN=32 fused-residual GEMM: grid (N/32, M/64) = 768 blocks (balanced)
static inline void launch_gemm32(const u16* A, const u16* W, const float* bias,
                                 const float* posr, float* y, int addy,
                                 int M, int N, int K, hipStream_t s) {
    dim3 g(N / 32, M / 64, 1);
    mfma_gemm32<<<g, 256, 0, s>>>(A, W, bias, posr, y, addy, M, N, K);
}

// BM=64/BN=32 bf16-out GEMM (qkv): grid (36, 64) = 2304 blocks = 9/CU exact
static inline void launch_gemm32b(const u16* A, const u16* W, const float* bias,
                                  u16* outb, int M, int N, int K, hipStream_t s) {
    dim3 g(N / 32, M / 64, 1);
    mfma_gemm32b<<<g, 256, 0, s>>>(A, W, bias, outb, M, N, K);
}

extern "C" void kernel_launch(void* const* d_in, const int* in_sizes, int n_in,
                              void* d_out, int out_size, void* d_ws, size_t ws_size,
                              hipStream_t stream) {
    const float* x      = (const float*)d_in[0];
    const float* patchw = (const float*)d_in[1];
    const float* patchb = (const float*)d_in[2];
    const float* pos    = (const float*)d_in[3];
    const float* n1w    = (const float*)d_in[4];
    const float* n1b    = (const float*)d_in[5];
    const float* qkvw   = (const float*)d_in[6];
    const float* qkvb   = (const float*)d_in[7];
    const float* pw     = (const float*)d_in[8];
    const float* pb     = (const float*)d_in[9];
    const float* n2w    = (const float*)d_in[10];
    const float* n2b    = (const float*)d_in[11];
    const float* f1w    = (const float*)d_in[12];
    const float* f1b    = (const float*)d_in[13];
    const float* f2w    = (const float*)d_in[14];
    const float* f2b    = (const float*)d_in[15];
    const float* rph    = (const float*)d_in[16];
    const float* rpw    = (const float*)d_in[17];
    float* out = (float*)d_out;

    // workspace layout (unchanged). Overlays cover only dead buffers:
    //  colb = rsrv (im2col, patch phase only)
    //  Opart = mlpb (global-attn phase), Lpart = lnb (dead post-qkv)
    float* y   = (float*)d_ws;                  // 1,572,864 f32
    u16* attb  = (u16*)(y + 1572864);           // 1,572,864 u16 (token layout)
    u16* mlpb  = attb + 1572864;                // 6,291,456 u16
    u16* lnb   = mlpb + 6291456;                // 1,572,864 u16
    u16* qkvx  = lnb + 1572864;                 // 4,718,592 u16 (4096x1152)
    u16* rsrv  = qkvx + 4718592;                // 7,864,320 u16
    u16* wb    = rsrv + 7864320;                // 10,918,656 u16 (weights + qkv bias)
    float* posr = (float*)(wb + 10918656);      //   393,216 f32

    u16* colb  = rsrv;                          // overlay: im2col 3,145,728 u16
    float* Opart   = (float*)mlpb;              // 2x24576x64 f32 = 12,582,912 B
    float* Lpart   = (float*)lnb;               // 2x24576 f32

    u16* wb_patch = wb;
    u16* wb_qkv   = wb + 294912;
    u16* wb_pw    = wb + 2949120;
    u16* wb_f1    = wb + 3833856;
    u16* wb_f2    = wb + 7372800;
    u16* wqb      = wb + 10911744;              // bf16 qkv bias, 6 x 1152

    setup_kernel<<<(14457600 / 4 + 255) / 256, 256, 0, stream>>>(
        patchw, qkvw, pw, f1w, f2w, qkvb, wb, pos, posr, x, colb);

    // patch embed: fused bias + pos-embed -> y (f32), then LN -> lnb
    launch_gemm32(colb, wb_patch, patchb, posr, y, 0, NTOK, 384, 768, stream);
    ln_kernel<<<1024, 256, 0, stream>>>(y, n1w, n1b, lnb);

    for (int i = 0; i < 6; ++i) {
        bool windowed = (i == 0 || i == 1 || i == 3 || i == 4);
        const float* rh = rph + (size_t)i * 63 * 64;
        const float* rw = rpw + (size_t)i * 63 * 64;
        // qkv: balanced 2304-block BN=32 GEMM (9 blocks/CU exact)
        launch_gemm32b(lnb, wb_qkv + (size_t)i * 442368, qkvb + i * 1152,
                       qkvx, NTOK, 1152, 384, stream);
        if (windowed) {
            attn_mfma<WTOK, WS><<<dim3(NWIN * HEADS, 4, 1), 256, 0, stream>>>(
                qkvx, wqb + i * 1152, rh, rw, attb, nullptr, nullptr);
        } else {
            attn_mfma<1024, 32><<<dim3(B_SZ * HEADS, 16, 2), 256, 0, stream>>>(
                qkvx, wqb + i * 1152, rh, rw, nullptr, Opart, Lpart);
            attn_merge_kernel<<<1536, 256, 0, stream>>>(Opart, Lpart, attb);
        }
        // proj: fused bias + residual accumulate onto y
        launch_gemm32(attb, wb_pw + (size_t)i * 147456, pb + i * 384,
                      nullptr, y, 1, NTOK, 384, 384, stream);
        ln_kernel<<<1024, 256, 0, stream>>>(y, n2w + i * 384, n2b + i * 384, lnb);
        launch_gemm(lnb, wb_f1 + (size_t)i * 589824, f1b + i * 1536,
                    mlpb, NTOK, 1536, 384, 1, stream);
        // fc2: fused bias + residual accumulate onto y
        launch_gemm32(mlpb, wb_f2 + (size_t)i * 589824, f2b + i * 384,
                      nullptr, y, 1, NTOK, 384, 1536, stream);
        if (i < 5)
            ln_kernel<<<1024, 256, 0, stream>>>(y, n1w + (i + 1) * 384,
                                                n1b + (i + 1) * 384, lnb);
        else
            out_transpose<<<dim3(6, 64), 256, 0, stream>>>(y, out);
    }
}

// Round 8
// 654.496 us; speedup vs baseline: 1.0859x; 1.0453x over previous
//
#include <hip/hip_runtime.h>
#include <hip/hip_bf16.h>
#include <math.h>

// ---------------- constants ----------------
#define B_SZ 4
#define DIM 384
#define HEADS 6
#define HD 64
#define NTOK 4096          // B*32*32
#define WS 14
#define NWIN 36            // B * 9
#define WTOK 196           // 14*14

typedef unsigned short u16;
typedef __bf16 bf16_t;
typedef bf16_t bf16x8 __attribute__((ext_vector_type(8)));
typedef float f32x4 __attribute__((ext_vector_type(4)));

__device__ __forceinline__ float bf2f(unsigned u) { return __uint_as_float(u << 16); }
__device__ __forceinline__ u16 f2bf(float f) {
    unsigned u = __float_as_uint(f);
    unsigned r = (u + 0x7fffu + ((u >> 16) & 1u)) >> 16;
    return (u16)r;
}
// packed RNE f32x2 -> bf16x2 (hardware v_cvt_pk_bf16_f32 on gfx950)
__device__ __forceinline__ unsigned pk2bf(float a, float b) {
    __hip_bfloat162 h = __float22bfloat162_rn(make_float2(a, b));
    unsigned r; __builtin_memcpy(&r, &h, 4); return r;
}

// async global->LDS, 16B per lane, wave-uniform LDS base + lane*16
__device__ __forceinline__ void ldsload16(const u16* g, u16* l) {
    __builtin_amdgcn_global_load_lds(
        (const __attribute__((address_space(1))) unsigned int*)g,
        (__attribute__((address_space(3))) unsigned int*)l, 16, 0, 0);
}

__device__ __forceinline__ int swz(int r) { return (r ^ (r >> 2)) & 3; }

// XCD-aware block remap (T1): dispatch id d runs on XCD d%8; remapping the
// LOGICAL block to (d%8)*cpx + d/8 gives each XCD a contiguous run of logical
// blocks, so blocks sharing an A-panel (same by) hit the same XCD L2.
// Bijective iff nwg % 8 == 0 (all GEMM grids here are 576 or 768).
__device__ __forceinline__ void xcd_remap(int& bx, int& by) {
    int nwg = gridDim.x * gridDim.y;
    int id = blockIdx.y * gridDim.x + blockIdx.x;
    if ((nwg & 7) == 0) {
        int nid = (id & 7) * (nwg >> 3) + (id >> 3);
        by = nid / gridDim.x;
        bx = nid - by * gridDim.x;
    } else {
        bx = blockIdx.x; by = blockIdx.y;
    }
}

// ---------------- bicubic helper ----------------
__device__ inline float cubic_keys(float x) {
    x = fabsf(x);
    if (x <= 1.f) return ((1.5f * x - 2.5f) * x) * x + 1.f;
    if (x < 2.f)  return ((-0.5f * x + 2.5f) * x - 4.f) * x + 2.f;
    return 0.f;
}

// ---------------- one-shot setup (x4 vectorized) -----------------------------
__global__ __launch_bounds__(256) void setup_kernel(
        const float* __restrict__ p0, const float* __restrict__ p1,
        const float* __restrict__ p2, const float* __restrict__ p3,
        const float* __restrict__ p4, const float* __restrict__ p5,
        u16* __restrict__ wb, const float* __restrict__ pe,
        float* __restrict__ posr, const float* __restrict__ x,
        u16* __restrict__ col) {
    int i = (blockIdx.x * 256 + threadIdx.x) * 4;
    if (i < 10918656) {
        const float* s; int off;
        if      (i <   294912) { s = p0; off = 0; }
        else if (i <  2949120) { s = p1; off = 294912; }
        else if (i <  3833856) { s = p2; off = 2949120; }
        else if (i <  7372800) { s = p3; off = 3833856; }
        else if (i < 10911744) { s = p4; off = 7372800; }
        else                   { s = p5; off = 10911744; }
        float4 v = *(const float4*)(s + (i - off));
        u16 o[4] = { f2bf(v.x), f2bf(v.y), f2bf(v.z), f2bf(v.w) };
        *(uint2*)(wb + i) = *(const uint2*)o;
        return;
    }
    i -= 10918656;
    if (i < 393216) {
        int c = i % 384;
        int g = i / 384;
        int gy = g / 32, gx = g % 32;
        float wy[14], wx[14];
        float sy = (gy + 0.5f) * (14.f / 32.f) - 0.5f;
        float sx = (gx + 0.5f) * (14.f / 32.f) - 0.5f;
        float toty = 0.f, totx = 0.f;
        #pragma unroll
        for (int k = 0; k < 14; ++k) {
            wy[k] = cubic_keys(sy - (float)k); toty += wy[k];
            wx[k] = cubic_keys(sx - (float)k); totx += wx[k];
        }
        float4 acc = {0.f, 0.f, 0.f, 0.f};
        #pragma unroll 1
        for (int iy = 0; iy < 14; ++iy) {
            if (wy[iy] == 0.f) continue;
            float4 row = {0.f, 0.f, 0.f, 0.f};
            for (int ix = 0; ix < 14; ++ix) {
                if (wx[ix] == 0.f) continue;
                float4 pv = *(const float4*)(pe + (iy * 14 + ix) * 384 + c);
                row.x += wx[ix] * pv.x; row.y += wx[ix] * pv.y;
                row.z += wx[ix] * pv.z; row.w += wx[ix] * pv.w;
            }
            acc.x += wy[iy] * row.x; acc.y += wy[iy] * row.y;
            acc.z += wy[iy] * row.z; acc.w += wy[iy] * row.w;
        }
        float inv = 1.f / (toty * totx);
        acc.x *= inv; acc.y *= inv; acc.z *= inv; acc.w *= inv;
        *(float4*)(posr + i) = acc;
        return;
    }
    i -= 393216;
    if (i < 3145728) {
        int kk = i % 768;
        int p  = i / 768;
        int b  = p / 1024;
        int ph = (p % 1024) / 32;
        int pw = p % 32;
        int c = kk / 256;
        int r = kk % 256;
        int ii = r / 16, j = r % 16;
        float4 v = *(const float4*)(x + (size_t)b * 3 * 512 * 512 +
                                    (size_t)c * 512 * 512 +
                                    (size_t)(ph * 16 + ii) * 512 + (pw * 16 + j));
        u16 o[4] = { f2bf(v.x), f2bf(v.y), f2bf(v.z), f2bf(v.w) };
        *(uint2*)(col + i) = *(const uint2*)o;
    }
}

// ---------------- slim LN kernel: y (f32) -> lnb (bf16) ----------------------
// 256 threads = 4 tokens/block (1 wave per token)
__global__ __launch_bounds__(256) void ln_kernel(const float* __restrict__ y,
        const float* __restrict__ lw, const float* __restrict__ lb,
        u16* __restrict__ lnout)
{
    int tok = blockIdx.x * 4 + (threadIdx.x >> 6);
    int t = threadIdx.x & 63;
    size_t base = (size_t)tok * 384;
    float v[6];
    float s = 0.f;
    #pragma unroll
    for (int i = 0; i < 6; ++i) {
        v[i] = y[base + t + 64 * i]; s += v[i];
    }
    #pragma unroll
    for (int off = 32; off > 0; off >>= 1) s += __shfl_xor(s, off);
    float mean = s * (1.f / 384.f);
    float vs = 0.f;
    #pragma unroll
    for (int i = 0; i < 6; ++i) { float d = v[i] - mean; vs += d * d; }
    #pragma unroll
    for (int off = 32; off > 0; off >>= 1) vs += __shfl_xor(vs, off);
    float inv = rsqrtf(vs * (1.f / 384.f) + 1e-5f);
    u16* orow = lnout + base;
    #pragma unroll
    for (int i = 0; i < 6; ++i) {
        int c = t + 64 * i;
        orow[c] = f2bf((v[i] - mean) * inv * lw[c] + lb[c]);
    }
}

// ---------------- coalesced NHWC(f32 y) -> NCHW out via LDS transpose --------
__global__ __launch_bounds__(256) void out_transpose(const float* __restrict__ y,
        float* __restrict__ outT)
{
    __shared__ float T[64][65];
    int c0 = blockIdx.x * 64, m0 = blockIdx.y * 64;
    int t = threadIdx.x;
    int cl = t & 63, wv = t >> 6;
    #pragma unroll
    for (int r = 0; r < 16; ++r) {
        int ml = wv * 16 + r;
        T[ml][cl] = y[(size_t)(m0 + ml) * 384 + c0 + cl];
    }
    __syncthreads();
    int b = m0 >> 10, g0 = m0 & 1023;
    int gl = t & 63;
    #pragma unroll
    for (int r = 0; r < 16; ++r) {
        int ccl = wv * 16 + r;
        outT[((size_t)(b * 384 + c0 + ccl)) * 1024 + g0 + gl] = T[gl][ccl];
    }
}

// ---------------- MFMA bf16 GEMM v4: BM=128, BN=64, BK=64, dbuf --------------
// used for qkv (grid (18,32)=576) and fc1 (GELU, grid (24,32)=768); XCD-swizzled
__global__ __launch_bounds__(256) void mfma_gemm4(
        const u16* __restrict__ A, const u16* __restrict__ Wt,
        const float* __restrict__ bias,
        u16* __restrict__ outb,
        int M, int N, int K, int act)
{
    __shared__ u16 As[2][8192];
    __shared__ u16 Bs[2][4096];
    int t = threadIdx.x;
    int lane = t & 63, wave = t >> 6;
    int wm = (wave >> 1) * 64, wn = (wave & 1) * 32;
    int bx, by;
    xcd_remap(bx, by);
    int m0 = by * 128, n0 = bx * 64;

    int r0 = t >> 2,        c0 = ((t & 3) ^ swz(t >> 2)) * 8;
    int r1 = 64 + (t >> 2), c1 = ((t & 3) ^ swz(64 + (t >> 2))) * 8;
    const u16* a0 = A + (size_t)(m0 + r0) * K + c0;
    const u16* a1 = A + (size_t)(m0 + r1) * K + c1;
    const u16* b0 = Wt + (size_t)(n0 + r0) * K + c0;

    auto stage = [&](int k0, int buf) {
        ldsload16(a0 + k0,      &As[buf][wave * 512]);
        ldsload16(a1 + k0,      &As[buf][2048 + wave * 512]);
        ldsload16(b0 + k0,      &Bs[buf][wave * 512]);
        ldsload16(a0 + k0 + 32, &As[buf][4096 + wave * 512]);
        ldsload16(a1 + k0 + 32, &As[buf][6144 + wave * 512]);
        ldsload16(b0 + k0 + 32, &Bs[buf][2048 + wave * 512]);
    };

    f32x4 acc[4][2] = {};
    int row_a = wm + (lane & 15);
    int row_b = wn + (lane & 15);
    int lq = lane >> 4;
    int nchunks = K / 64;

    stage(0, 0);
    __syncthreads();

    for (int ci = 0; ci < nchunks; ++ci) {
        int p = ci & 1;
        bool pref = (ci + 1 < nchunks);
        if (pref) stage((ci + 1) * 64, 1 - p);
        #pragma unroll
        for (int hf = 0; hf < 2; ++hf) {
            bf16x8 af[4], bfr[2];
            #pragma unroll
            for (int i = 0; i < 4; ++i) {
                int r = row_a + i * 16;
                af[i] = *(const bf16x8*)&As[p][hf * 4096 + r * 32 + ((lq ^ swz(r)) * 8)];
            }
            #pragma unroll
            for (int j = 0; j < 2; ++j) {
                int r = row_b + j * 16;
                bfr[j] = *(const bf16x8*)&Bs[p][hf * 2048 + r * 32 + ((lq ^ swz(r)) * 8)];
            }
            #pragma unroll
            for (int i = 0; i < 4; ++i)
                #pragma unroll
                for (int j = 0; j < 2; ++j)
                    acc[i][j] = __builtin_amdgcn_mfma_f32_16x16x32_bf16(
                        af[i], bfr[j], acc[i][j], 0, 0, 0);
        }
        if (pref) __syncthreads();
    }

    int colq = lane & 15, rowq = (lane >> 4) * 4;
    #pragma unroll
    for (int i = 0; i < 4; ++i) {
        #pragma unroll
        for (int rr = 0; rr < 4; ++rr) {
            int m = m0 + wm + i * 16 + rowq + rr;
            size_t mo = (size_t)m * N;
            #pragma unroll
            for (int j = 0; j < 2; ++j) {
                int n = n0 + wn + j * 16 + colq;
                float v = acc[i][j][rr] + bias[n];
                if (act)  v = 0.5f * v * (1.f + erff(v * 0.70710678118654752f));
                outb[mo + n] = f2bf(v);
            }
        }
    }
}

// ---------------- MFMA bf16 GEMM 64x32: fused residual epilogue --------------
// N=384: grid (12, M/64) = 768 blocks = 3/CU exactly (balanced); XCD-swizzled
__global__ __launch_bounds__(256) void mfma_gemm32(
        const u16* __restrict__ A, const u16* __restrict__ Wt,
        const float* __restrict__ bias, const float* __restrict__ posr,
        float* __restrict__ y, int addy, int M, int N, int K)
{
    __shared__ u16 As[2][4096];
    __shared__ u16 Bs[2][2048];
    int t = threadIdx.x;
    int lane = t & 63, wave = t >> 6;
    int wm = (wave >> 1) * 32, wn = (wave & 1) * 16;
    int bx, by;
    xcd_remap(bx, by);
    int m0 = by * 64, n0 = bx * 32;

    int r0 = t >> 2, c0 = ((t & 3) ^ swz(t >> 2)) * 8;
    const u16* a0 = A + (size_t)(m0 + r0) * K + c0;
    int tb = t & 127;
    int rb = tb >> 2, cb = ((tb & 3) ^ swz(tb >> 2)) * 8;
    const u16* b0 = Wt + (size_t)(n0 + rb) * K + cb;

    auto stage = [&](int k0, int buf) {
        ldsload16(a0 + k0,      &As[buf][wave * 512]);
        ldsload16(a0 + k0 + 32, &As[buf][2048 + wave * 512]);
        if (wave < 2) ldsload16(b0 + k0,      &Bs[buf][wave * 512]);
        else          ldsload16(b0 + k0 + 32, &Bs[buf][1024 + (wave - 2) * 512]);
    };

    f32x4 acc[2] = {};
    int row_a = wm + (lane & 15);
    int row_b = wn + (lane & 15);
    int lq = lane >> 4;
    int nchunks = K / 64;

    stage(0, 0);
    __syncthreads();

    for (int ci = 0; ci < nchunks; ++ci) {
        int p = ci & 1;
        bool pref = (ci + 1 < nchunks);
        if (pref) stage((ci + 1) * 64, 1 - p);
        #pragma unroll
        for (int hf = 0; hf < 2; ++hf) {
            bf16x8 af[2], bf0;
            #pragma unroll
            for (int i = 0; i < 2; ++i) {
                int r = row_a + i * 16;
                af[i] = *(const bf16x8*)&As[p][hf * 2048 + r * 32 + ((lq ^ swz(r)) * 8)];
            }
            {
                int r = row_b;
                bf0 = *(const bf16x8*)&Bs[p][hf * 1024 + r * 32 + ((lq ^ swz(r)) * 8)];
            }
            #pragma unroll
            for (int i = 0; i < 2; ++i)
                acc[i] = __builtin_amdgcn_mfma_f32_16x16x32_bf16(
                    af[i], bf0, acc[i], 0, 0, 0);
        }
        if (pref) __syncthreads();
    }

    int colq = lane & 15, rowq = (lane >> 4) * 4;
    #pragma unroll
    for (int i = 0; i < 2; ++i) {
        #pragma unroll
        for (int rr = 0; rr < 4; ++rr) {
            int m = m0 + wm + i * 16 + rowq + rr;
            size_t mo = (size_t)m * N;
            int n = n0 + wn + colq;
            float v = acc[i][rr] + bias[n];
            if (posr) v += posr[(size_t)(m & 1023) * 384 + n];
            if (addy) v += y[mo + n];
            y[mo + n] = v;
        }
    }
}

// ---------------- MFMA flash attention ---------------------------------------
// W==32: global, grid (24, 16, 2) -- key-split 2, unnormalized partials out.
// W==14: windowed, grid (216, 4, 1) -- direct bf16 out; kofs LDS bias-index
//        table replaces incremental coords; fully-invalid query waves skip
//        compute (still stage K/V + hit barriers).
template<int N, int W>
__global__ __launch_bounds__(256) void attn_mfma(const u16* __restrict__ qkv,
        const u16* __restrict__ qkb, const float* __restrict__ rh,
        const float* __restrict__ rw, u16* __restrict__ outb,
        float* __restrict__ opart, float* __restrict__ lpart)
{
    constexpr int JS = (W == 32) ? 64 : 32;
    constexpr int L  = (W == 32) ? 63 : 27;
    constexpr int CTR = W - 1;
    constexpr int KSPAN = (W == 32) ? 512 : 224;
    constexpr int NKT = KSPAN / 32;
    __shared__ u16 KV[11776];  // Ks[2][2048] | Vt[2][2560] | Pb[2560]
    __shared__ u16 bhl[64 * 66];
    __shared__ u16 bwl[64 * 66];
    __shared__ u16 Qt[64 * 66];
    __shared__ unsigned kofs[224];   // W==14: (kh | kw<<16) per key

    u16* Pb = KV + 9216;
    u16* Rt = KV;

    int t = threadIdx.x, lane = t & 63, wave = t >> 6;
    int quad = lane >> 4, l15 = lane & 15;
    int uh = blockIdx.x, qb0 = blockIdx.y * 64;
    int z = (W == 32) ? blockIdx.z : 0;
    int kstart = z * KSPAN;
    int h = uh % HEADS, u = uh / HEADS;
    size_t tbase = (size_t)u * 1024;
    int wb_ = u / 9, wr = u - wb_ * 9;
    int wy = wr / 3, wx = wr - wy * 3;

    auto tok14 = [&](int iy, int ix) -> const u16* {
        int gy = wy * WS + iy, gx = wx * WS + ix;
        if (gy < 32 && gx < 32)
            return qkv + (size_t)(wb_ * 1024 + gy * 32 + gx) * 1152;
        return qkb;
    };
    auto rowptr = [&](int lq2) -> const u16* {   // div-based, prologue only
        if constexpr (W == 32) {
            return qkv + (tbase + lq2) * 1152;
        } else {
            int iy = lq2 / WS, ix = lq2 - iy * WS;
            return tok14(iy, ix);
        }
    };

    // ---- stage Q^T (unscaled) ----
    {
        int q = t & 63, ch0 = (t >> 6) * 16;
        int qc = qb0 + q; if (qc >= N) qc = N - 1;
        const u16* qp = rowptr(qc) + h * 64 + ch0;
        uint4 a = *(const uint4*)qp;
        uint4 b = *(const uint4*)(qp + 8);
        u16 vals[16];
        *(uint4*)vals = a; *(uint4*)(vals + 8) = b;
        #pragma unroll
        for (int c = 0; c < 16; ++c)
            Qt[(ch0 + c) * 66 + q] = ((qb0 + q) < N) ? vals[c] : (u16)0;
    }

    // ---- W==14: key -> (kh,kw) LDS table ----
    if constexpr (W != 32) {
        if (t < 224) {
            int kh = t / WS;
            kofs[t] = (unsigned)kh | ((unsigned)(t - kh * WS) << 16);
        }
    }

    // ---- stage BOTH rel-pos tables (bf16) into Rt ----
    for (int idx = t; idx < JS * 16; idx += 256) {
        int table = (idx >= JS * 8) ? 1 : 0;
        int id2 = idx & (JS * 8 - 1);
        int j = id2 >> 3, cc0 = (id2 & 7) * 8;
        const float* tab = table ? rw : rh;
        u16 tmp[8];
        if (j < L) {
            const float* src = tab + (size_t)j * 64 + cc0;
            #pragma unroll
            for (int c = 0; c < 8; ++c) tmp[c] = f2bf(src[c]);
        } else {
            #pragma unroll
            for (int c = 0; c < 8; ++c) tmp[c] = 0;
        }
        *(uint4*)&Rt[table * JS * 72 + j * 72 + cc0] = *(uint4*)tmp;
    }
    __syncthreads();

    // ---- bias-table MFMAs D = Q . R^T (one phase, both tables) ----
    {
        int tb0 = (W == 32) ? 0 : (wave >> 1);
        int ntb = (W == 32) ? 2 : 1;
        int jt  = (W == 32) ? wave : (wave & 1);
        for (int tt = 0; tt < ntb; ++tt) {
            int table = tb0 + tt;
            const u16* Rtt = Rt + table * JS * 72;
            bf16x8 af0 = *(const bf16x8*)&Rtt[(jt * 16 + l15) * 72 + quad * 8];
            bf16x8 af1 = *(const bf16x8*)&Rtt[(jt * 16 + l15) * 72 + 32 + quad * 8];
            u16* dst = table ? bwl : bhl;
            #pragma unroll
            for (int qt = 0; qt < 4; ++qt) {
                bf16x8 qf0, qf1;
                u16* p0 = (u16*)&qf0; u16* p1 = (u16*)&qf1;
                #pragma unroll
                for (int zz = 0; zz < 8; ++zz) {
                    p0[zz] = Qt[(quad * 8 + zz) * 66 + qt * 16 + l15];
                    p1[zz] = Qt[(32 + quad * 8 + zz) * 66 + qt * 16 + l15];
                }
                f32x4 acc = {};
                acc = __builtin_amdgcn_mfma_f32_16x16x32_bf16(af0, qf0, acc, 0, 0, 0);
                acc = __builtin_amdgcn_mfma_f32_16x16x32_bf16(af1, qf1, acc, 0, 0, 0);
                #pragma unroll
                for (int r = 0; r < 4; ++r)
                    dst[(qt * 16 + l15) * 66 + jt * 16 + quad * 4 + r] = f2bf(acc[r]);
            }
        }
    }
    __syncthreads();

    // ---- per-lane staging coordinates (incremental for W==14) ----
    int skey = (wave * 64 + lane) >> 3;             // K-stage key (0..31)
    int sc8  = ((wave * 64 + lane) & 7) ^ (skey & 7);
    int vkey = t & 31, vch0 = (t >> 5) * 8;         // V-stage key/ch
    int siy = 0, six = 0, viy = 0, vix = 0;
    if constexpr (W != 32) {
        int k0 = kstart + skey;   // kstart==0
        siy = k0 / WS; six = k0 - siy * WS;
        int k1 = kstart + vkey;
        viy = k1 / WS; vix = k1 - viy * WS;
    }
    auto adv = [](int& iy, int& ix) { ix += 4; iy += 2; if (ix >= WS) { ix -= WS; ++iy; } };

    // ---- stage tile 0 into buffer 0 ----
    {
        const u16* kp = (W == 32) ? qkv + (tbase + kstart + skey) * 1152
                                  : tok14(siy, six);
        ldsload16(kp + 384 + h * 64 + sc8 * 8, KV + wave * 512);
        const u16* vp = (W == 32) ? qkv + (tbase + kstart + vkey) * 1152
                                  : tok14(viy, vix);
        uint4 vv = *(const uint4*)(vp + 768 + h * 64 + vch0);
        u16 tmp[8]; *(uint4*)tmp = vv;
        u16* vdst = KV + 4096;
        #pragma unroll
        for (int c = 0; c < 8; ++c) vdst[(vch0 + c) * 40 + vkey] = tmp[c];
        if constexpr (W != 32) { adv(siy, six); adv(viy, vix); }
    }

    // Q^T B-frags (loop-invariant; scale applied to scores)
    bf16x8 qf[2];
    #pragma unroll
    for (int hc = 0; hc < 2; ++hc) {
        u16* qv = (u16*)&qf[hc];
        #pragma unroll
        for (int j = 0; j < 8; ++j)
            qv[j] = Qt[(hc * 32 + quad * 8 + j) * 66 + wave * 16 + l15];
    }
    int qme = wave * 16 + l15;
    // wave-uniform: does this wave's 16-query tile contain any valid query?
    bool wactive = (W == 32) ? true : ((qb0 + wave * 16) < N);
    int qq = qb0 + qme; if (qq >= N) qq = N - 1;
    int qh = qq / W, qw = qq - qh * W;
    int qh13 = qh + CTR, qw13 = qw + CTR;
    float bwreg[2][4];
    if constexpr (W == 32) {
        #pragma unroll
        for (int kc2 = 0; kc2 < 2; ++kc2)
            #pragma unroll
            for (int r = 0; r < 4; ++r) {
                int keyl = kc2 * 16 + quad * 4 + r;
                bwreg[kc2][r] = bf2f(bwl[qme * 66 + (qw - keyl + CTR)]);
            }
    }

    f32x4 of[4] = {};
    float lsum = 0.f;
    __syncthreads();   // tile 0 staged (vmcnt drained)

    for (int kt = 0; kt < NKT; ++kt) {
        int kb = kstart + kt * 32;
        int p = kt & 1;
        const u16* ksp = KV + p * 2048;
        const u16* vtp = KV + 4096 + p * 2560;
        bool pref = (kt + 1 < NKT);
        uint4 vpref;
        if (pref) {
            const u16* kp = (W == 32) ? qkv + (tbase + kb + 32 + skey) * 1152
                                      : tok14(siy, six);
            ldsload16(kp + 384 + h * 64 + sc8 * 8, KV + (1 - p) * 2048 + wave * 512);
            const u16* vp = (W == 32) ? qkv + (tbase + kb + 32 + vkey) * 1152
                                      : tok14(viy, vix);
            vpref = *(const uint4*)(vp + 768 + h * 64 + vch0);
            if constexpr (W != 32) { adv(siy, six); adv(viy, vix); }
        }

        // ---- compute tile kt (skipped by fully-invalid query waves) ----
        if (wactive) {
            f32x4 st[2] = {};
            #pragma unroll
            for (int hc = 0; hc < 2; ++hc) {
                #pragma unroll
                for (int kc2 = 0; kc2 < 2; ++kc2) {
                    int key = kc2 * 16 + l15;
                    int c8 = hc * 4 + quad;
                    int pp = key * 8 + (c8 ^ (key & 7));
                    bf16x8 kf = *(const bf16x8*)&ksp[pp * 8];
                    st[kc2] = __builtin_amdgcn_mfma_f32_16x16x32_bf16(
                        kf, qf[hc], st[kc2], 0, 0, 0);
                }
            }
            float bh_t = 0.f;
            if constexpr (W == 32) bh_t = bf2f(bhl[qme * 66 + (qh - (kb >> 5) + CTR)]);
            #pragma unroll
            for (int kc2 = 0; kc2 < 2; ++kc2) {
                float pv4[4];
                #pragma unroll
                for (int r = 0; r < 4; ++r) {
                    int keyl = kc2 * 16 + quad * 4 + r;
                    float pv;
                    if constexpr (W == 32) {
                        float b = bh_t + bwreg[kc2][r];
                        pv = __expf(fmaf(st[kc2][r], 0.125f, b));
                    } else {
                        unsigned ko = kofs[kb + keyl];
                        float b = bf2f(bhl[qme * 66 + qh13 - (int)(ko & 0xffffu)]) +
                                  bf2f(bwl[qme * 66 + qw13 - (int)(ko >> 16)]);
                        pv = __expf(fmaf(st[kc2][r], 0.125f, b));
                        if (kb + keyl >= N) pv = 0.f;
                    }
                    lsum += pv;
                    pv4[r] = pv;
                }
                uint2 pk;
                pk.x = pk2bf(pv4[0], pv4[1]);
                pk.y = pk2bf(pv4[2], pv4[3]);
                *(uint2*)&Pb[wave * 640 + l15 * 40 + kc2 * 16 + quad * 4] = pk;
            }
            bf16x8 pf = *(const bf16x8*)&Pb[wave * 640 + l15 * 40 + quad * 8];
            #pragma unroll
            for (int ca = 0; ca < 4; ++ca) {
                bf16x8 vf = *(const bf16x8*)&vtp[(ca * 16 + l15) * 40 + quad * 8];
                of[ca] = __builtin_amdgcn_mfma_f32_16x16x32_bf16(
                    vf, pf, of[ca], 0, 0, 0);
            }
        }

        if (pref) {
            u16 tmp[8]; *(uint4*)tmp = vpref;
            u16* vdst = KV + 4096 + (1 - p) * 2560;
            #pragma unroll
            for (int c = 0; c < 8; ++c) vdst[(vch0 + c) * 40 + vkey] = tmp[c];
            __syncthreads();
        }
    }

    lsum += __shfl_xor(lsum, 16);
    lsum += __shfl_xor(lsum, 32);
    int q = qb0 + qme;
    if constexpr (W == 32) {
        // unnormalized partials: O fp32 + l
        size_t ridx = (size_t)z * 24576 + (size_t)uh * 1024 + q;
        float* op = opart + ridx * 64;
        #pragma unroll
        for (int ca = 0; ca < 4; ++ca)
            *(float4*)&op[ca * 16 + quad * 4] = (float4){of[ca][0], of[ca][1],
                                                         of[ca][2], of[ca][3]};
        if (quad == 0) lpart[ridx] = lsum;
    } else {
        float inv = 1.f / lsum;
        if (q < N) {
            int iy = q / WS, ix = q - iy * WS;
            int gy = wy * WS + iy, gx = wx * WS + ix;
            if (gy >= 32 || gx >= 32) return;
            u16* op = outb + (size_t)(wb_ * 1024 + gy * 32 + gx) * 384 + h * 64;
            #pragma unroll
            for (int ca = 0; ca < 4; ++ca) {
                uint2 pk;
                pk.x = pk2bf(of[ca][0] * inv, of[ca][1] * inv);
                pk.y = pk2bf(of[ca][2] * inv, of[ca][3] * inv);
                *(uint2*)&op[ca * 16 + quad * 4] = pk;
            }
        }
    }
}

// ---------------- merge split-key attention partials (x4 vectorized) ---------
__global__ __launch_bounds__(256) void attn_merge_kernel(const float* __restrict__ O,
        const float* __restrict__ Lp, u16* __restrict__ attb)
{
    int gi = blockIdx.x * 256 + threadIdx.x;   // 393216 threads, 4 ch each
    int idx = gi >> 4;                          // uh*1024 + q
    int ch = (gi & 15) * 4;
    float4 o0 = *(const float4*)&O[(size_t)idx * 64 + ch];
    float4 o1 = *(const float4*)&O[((size_t)24576 + idx) * 64 + ch];
    float inv = 1.f / (Lp[idx] + Lp[24576 + idx]);
    int uh = idx >> 10, q = idx & 1023;
    int u = uh / 6, h = uh - u * 6;
    uint2 pk;
    pk.x = pk2bf((o0.x + o1.x) * inv, (o0.y + o1.y) * inv);
    pk.y = pk2bf((o0.z + o1.z) * inv, (o0.w + o1.w) * inv);
    *(uint2*)(attb + ((size_t)(u * 1024 + q)) * 384 + h * 64 + ch) = pk;
}

// ---------------- host helpers ----------------
static inline void launch_gemm(const u16* A, const u16* W, const float* bias,
                               u16* outb, int M, int N, int K, int act,
                               hipStream_t s) {
    dim3 g(N / 64, M / 128, 1);
    mfma_gemm4<<<g, 256, 0, s>>>(A, W, bias, outb, M, N, K, act);
}

// BM=64/BN=32 fused-residual GEMM: grid (N/32, M/64) = 768 blocks (balanced)
static inline void launch_gemm32(const u16* A, const u16* W, const float* bias,
                                 const float* posr, float* y, int addy,
                                 int M, int N, int K, hipStream_t s) {
    dim3 g(N / 32, M / 64, 1);
    mfma_gemm32<<<g, 256, 0, s>>>(A, W, bias, posr, y, addy, M, N, K);
}

extern "C" void kernel_launch(void* const* d_in, const int* in_sizes, int n_in,
                              void* d_out, int out_size, void* d_ws, size_t ws_size,
                              hipStream_t stream) {
    const float* x      = (const float*)d_in[0];
    const float* patchw = (const float*)d_in[1];
    const float* patchb = (const float*)d_in[2];
    const float* pos    = (const float*)d_in[3];
    const float* n1w    = (const float*)d_in[4];
    const float* n1b    = (const float*)d_in[5];
    const float* qkvw   = (const float*)d_in[6];
    const float* qkvb   = (const float*)d_in[7];
    const float* pw     = (const float*)d_in[8];
    const float* pb     = (const float*)d_in[9];
    const float* n2w    = (const float*)d_in[10];
    const float* n2b    = (const float*)d_in[11];
    const float* f1w    = (const float*)d_in[12];
    const float* f1b    = (const float*)d_in[13];
    const float* f2w    = (const float*)d_in[14];
    const float* f2b    = (const float*)d_in[15];
    const float* rph    = (const float*)d_in[16];
    const float* rpw    = (const float*)d_in[17];
    float* out = (float*)d_out;

    // workspace layout (unchanged). Overlays cover only dead buffers:
    //  colb = rsrv (im2col, patch phase only)
    //  Opart = mlpb (global-attn phase), Lpart = lnb (dead post-qkv)
    float* y   = (float*)d_ws;                  // 1,572,864 f32
    u16* attb  = (u16*)(y + 1572864);           // 1,572,864 u16 (token layout)
    u16* mlpb  = attb + 1572864;                // 6,291,456 u16
    u16* lnb   = mlpb + 6291456;                // 1,572,864 u16
    u16* qkvx  = lnb + 1572864;                 // 4,718,592 u16 (4096x1152)
    u16* rsrv  = qkvx + 4718592;                // 7,864,320 u16
    u16* wb    = rsrv + 7864320;                // 10,918,656 u16 (weights + qkv bias)
    float* posr = (float*)(wb + 10918656);      //   393,216 f32

    u16* colb  = rsrv;                          // overlay: im2col 3,145,728 u16
    float* Opart   = (float*)mlpb;              // 2x24576x64 f32 = 12,582,912 B
    float* Lpart   = (float*)lnb;               // 2x24576 f32

    u16* wb_patch = wb;
    u16* wb_qkv   = wb + 294912;
    u16* wb_pw    = wb + 2949120;
    u16* wb_f1    = wb + 3833856;
    u16* wb_f2    = wb + 7372800;
    u16* wqb      = wb + 10911744;              // bf16 qkv bias, 6 x 1152

    setup_kernel<<<(14457600 / 4 + 255) / 256, 256, 0, stream>>>(
        patchw, qkvw, pw, f1w, f2w, qkvb, wb, pos, posr, x, colb);

    // patch embed: fused bias + pos-embed -> y (f32), then LN -> lnb
    launch_gemm32(colb, wb_patch, patchb, posr, y, 0, NTOK, 384, 768, stream);
    ln_kernel<<<1024, 256, 0, stream>>>(y, n1w, n1b, lnb);

    for (int i = 0; i < 6; ++i) {
        bool windowed = (i == 0 || i == 1 || i == 3 || i == 4);
        const float* rh = rph + (size_t)i * 63 * 64;
        const float* rw = rpw + (size_t)i * 63 * 64;
        launch_gemm(lnb, wb_qkv + (size_t)i * 442368, qkvb + i * 1152,
                    qkvx, NTOK, 1152, 384, 0, stream);
        if (windowed) {
            attn_mfma<WTOK, WS><<<dim3(NWIN * HEADS, 4, 1), 256, 0, stream>>>(
                qkvx, wqb + i * 1152, rh, rw, attb, nullptr, nullptr);
        } else {
            attn_mfma<1024, 32><<<dim3(B_SZ * HEADS, 16, 2), 256, 0, stream>>>(
                qkvx, wqb + i * 1152, rh, rw, nullptr, Opart, Lpart);
            attn_merge_kernel<<<1536, 256, 0, stream>>>(Opart, Lpart, attb);
        }
        // proj: fused bias + residual accumulate onto y
        launch_gemm32(attb, wb_pw + (size_t)i * 147456, pb + i * 384,
                      nullptr, y, 1, NTOK, 384, 384, stream);
        ln_kernel<<<1024, 256, 0, stream>>>(y, n2w + i * 384, n2b + i * 384, lnb);
        launch_gemm(lnb, wb_f1 + (size_t)i * 589824, f1b + i * 1536,
                    mlpb, NTOK, 1536, 384, 1, stream);
        // fc2: fused bias + residual accumulate onto y
        launch_gemm32(mlpb, wb_f2 + (size_t)i * 589824, f2b + i * 384,
                      nullptr, y, 1, NTOK, 384, 1536, stream);
        if (i < 5)
            ln_kernel<<<1024, 256, 0, stream>>>(y, n1w + (i + 1) * 384,
                                                n1b + (i + 1) * 384, lnb);
        else
            out_transpose<<<dim3(6, 64), 256, 0, stream>>>(y, out);
    }
}

// Round 9
// 635.126 us; speedup vs baseline: 1.1190x; 1.0305x over previous
//
#include <hip/hip_runtime.h>
#include <hip/hip_bf16.h>
#include <math.h>

// ---------------- constants ----------------
#define B_SZ 4
#define DIM 384
#define HEADS 6
#define HD 64
#define NTOK 4096          // B*32*32
#define WS 14
#define NWIN 36            // B * 9
#define WTOK 196           // 14*14

typedef unsigned short u16;
typedef __bf16 bf16_t;
typedef bf16_t bf16x8 __attribute__((ext_vector_type(8)));
typedef float f32x4 __attribute__((ext_vector_type(4)));

__device__ __forceinline__ float bf2f(unsigned u) { return __uint_as_float(u << 16); }
__device__ __forceinline__ u16 f2bf(float f) {
    unsigned u = __float_as_uint(f);
    unsigned r = (u + 0x7fffu + ((u >> 16) & 1u)) >> 16;
    return (u16)r;
}
// packed RNE f32x2 -> bf16x2 (hardware v_cvt_pk_bf16_f32 on gfx950)
__device__ __forceinline__ unsigned pk2bf(float a, float b) {
    __hip_bfloat162 h = __float22bfloat162_rn(make_float2(a, b));
    unsigned r; __builtin_memcpy(&r, &h, 4); return r;
}

// async global->LDS, 16B per lane, wave-uniform LDS base + lane*16
__device__ __forceinline__ void ldsload16(const u16* g, u16* l) {
    __builtin_amdgcn_global_load_lds(
        (const __attribute__((address_space(1))) unsigned int*)g,
        (__attribute__((address_space(3))) unsigned int*)l, 16, 0, 0);
}

__device__ __forceinline__ int swz(int r) { return (r ^ (r >> 2)) & 3; }

// XCD-aware block remap (T1): dispatch id d runs on XCD d%8; remapping the
// LOGICAL block to (d%8)*cpx + d/8 gives each XCD a contiguous run of logical
// blocks, so blocks sharing an A-panel (same by) hit the same XCD L2.
// Bijective iff nwg % 8 == 0 (GEMM grids here: 576/768/1152).
__device__ __forceinline__ void xcd_remap(int& bx, int& by) {
    int nwg = gridDim.x * gridDim.y;
    int id = blockIdx.y * gridDim.x + blockIdx.x;
    if ((nwg & 7) == 0) {
        int nid = (id & 7) * (nwg >> 3) + (id >> 3);
        by = nid / gridDim.x;
        bx = nid - by * gridDim.x;
    } else {
        bx = blockIdx.x; by = blockIdx.y;
    }
}

// ---------------- bicubic helper ----------------
__device__ inline float cubic_keys(float x) {
    x = fabsf(x);
    if (x <= 1.f) return ((1.5f * x - 2.5f) * x) * x + 1.f;
    if (x < 2.f)  return ((-0.5f * x + 2.5f) * x - 4.f) * x + 2.f;
    return 0.f;
}

// ---------------- one-shot setup (x4 vectorized) -----------------------------
__global__ __launch_bounds__(256) void setup_kernel(
        const float* __restrict__ p0, const float* __restrict__ p1,
        const float* __restrict__ p2, const float* __restrict__ p3,
        const float* __restrict__ p4, const float* __restrict__ p5,
        u16* __restrict__ wb, const float* __restrict__ pe,
        float* __restrict__ posr, const float* __restrict__ x,
        u16* __restrict__ col) {
    int i = (blockIdx.x * 256 + threadIdx.x) * 4;
    if (i < 10918656) {
        const float* s; int off;
        if      (i <   294912) { s = p0; off = 0; }
        else if (i <  2949120) { s = p1; off = 294912; }
        else if (i <  3833856) { s = p2; off = 2949120; }
        else if (i <  7372800) { s = p3; off = 3833856; }
        else if (i < 10911744) { s = p4; off = 7372800; }
        else                   { s = p5; off = 10911744; }
        float4 v = *(const float4*)(s + (i - off));
        u16 o[4] = { f2bf(v.x), f2bf(v.y), f2bf(v.z), f2bf(v.w) };
        *(uint2*)(wb + i) = *(const uint2*)o;
        return;
    }
    i -= 10918656;
    if (i < 393216) {
        int c = i % 384;
        int g = i / 384;
        int gy = g / 32, gx = g % 32;
        float wy[14], wx[14];
        float sy = (gy + 0.5f) * (14.f / 32.f) - 0.5f;
        float sx = (gx + 0.5f) * (14.f / 32.f) - 0.5f;
        float toty = 0.f, totx = 0.f;
        #pragma unroll
        for (int k = 0; k < 14; ++k) {
            wy[k] = cubic_keys(sy - (float)k); toty += wy[k];
            wx[k] = cubic_keys(sx - (float)k); totx += wx[k];
        }
        float4 acc = {0.f, 0.f, 0.f, 0.f};
        #pragma unroll 1
        for (int iy = 0; iy < 14; ++iy) {
            if (wy[iy] == 0.f) continue;
            float4 row = {0.f, 0.f, 0.f, 0.f};
            for (int ix = 0; ix < 14; ++ix) {
                if (wx[ix] == 0.f) continue;
                float4 pv = *(const float4*)(pe + (iy * 14 + ix) * 384 + c);
                row.x += wx[ix] * pv.x; row.y += wx[ix] * pv.y;
                row.z += wx[ix] * pv.z; row.w += wx[ix] * pv.w;
            }
            acc.x += wy[iy] * row.x; acc.y += wy[iy] * row.y;
            acc.z += wy[iy] * row.z; acc.w += wy[iy] * row.w;
        }
        float inv = 1.f / (toty * totx);
        acc.x *= inv; acc.y *= inv; acc.z *= inv; acc.w *= inv;
        *(float4*)(posr + i) = acc;
        return;
    }
    i -= 393216;
    if (i < 3145728) {
        int kk = i % 768;
        int p  = i / 768;
        int b  = p / 1024;
        int ph = (p % 1024) / 32;
        int pw = p % 32;
        int c = kk / 256;
        int r = kk % 256;
        int ii = r / 16, j = r % 16;
        float4 v = *(const float4*)(x + (size_t)b * 3 * 512 * 512 +
                                    (size_t)c * 512 * 512 +
                                    (size_t)(ph * 16 + ii) * 512 + (pw * 16 + j));
        u16 o[4] = { f2bf(v.x), f2bf(v.y), f2bf(v.z), f2bf(v.w) };
        *(uint2*)(col + i) = *(const uint2*)o;
    }
}

// ---------------- slim LN kernel: y (f32) -> lnb (bf16) ----------------------
// 256 threads = 4 tokens/block (1 wave per token)
__global__ __launch_bounds__(256) void ln_kernel(const float* __restrict__ y,
        const float* __restrict__ lw, const float* __restrict__ lb,
        u16* __restrict__ lnout)
{
    int tok = blockIdx.x * 4 + (threadIdx.x >> 6);
    int t = threadIdx.x & 63;
    size_t base = (size_t)tok * 384;
    float v[6];
    float s = 0.f;
    #pragma unroll
    for (int i = 0; i < 6; ++i) {
        v[i] = y[base + t + 64 * i]; s += v[i];
    }
    #pragma unroll
    for (int off = 32; off > 0; off >>= 1) s += __shfl_xor(s, off);
    float mean = s * (1.f / 384.f);
    float vs = 0.f;
    #pragma unroll
    for (int i = 0; i < 6; ++i) { float d = v[i] - mean; vs += d * d; }
    #pragma unroll
    for (int off = 32; off > 0; off >>= 1) vs += __shfl_xor(vs, off);
    float inv = rsqrtf(vs * (1.f / 384.f) + 1e-5f);
    u16* orow = lnout + base;
    #pragma unroll
    for (int i = 0; i < 6; ++i) {
        int c = t + 64 * i;
        orow[c] = f2bf((v[i] - mean) * inv * lw[c] + lb[c]);
    }
}

// ---------------- coalesced NHWC(f32 y) -> NCHW out via LDS transpose --------
__global__ __launch_bounds__(256) void out_transpose(const float* __restrict__ y,
        float* __restrict__ outT)
{
    __shared__ float T[64][65];
    int c0 = blockIdx.x * 64, m0 = blockIdx.y * 64;
    int t = threadIdx.x;
    int cl = t & 63, wv = t >> 6;
    #pragma unroll
    for (int r = 0; r < 16; ++r) {
        int ml = wv * 16 + r;
        T[ml][cl] = y[(size_t)(m0 + ml) * 384 + c0 + cl];
    }
    __syncthreads();
    int b = m0 >> 10, g0 = m0 & 1023;
    int gl = t & 63;
    #pragma unroll
    for (int r = 0; r < 16; ++r) {
        int ccl = wv * 16 + r;
        outT[((size_t)(b * 384 + c0 + ccl)) * 1024 + g0 + gl] = T[gl][ccl];
    }
}

// ---------------- MFMA bf16 GEMM v4: BM=128, BN=64, BK=64, dbuf --------------
// used for fc1 (GELU, grid (24,32)=768 = 3/CU); XCD-swizzled
__global__ __launch_bounds__(256) void mfma_gemm4(
        const u16* __restrict__ A, const u16* __restrict__ Wt,
        const float* __restrict__ bias,
        u16* __restrict__ outb,
        int M, int N, int K, int act)
{
    __shared__ u16 As[2][8192];
    __shared__ u16 Bs[2][4096];
    int t = threadIdx.x;
    int lane = t & 63, wave = t >> 6;
    int wm = (wave >> 1) * 64, wn = (wave & 1) * 32;
    int bx, by;
    xcd_remap(bx, by);
    int m0 = by * 128, n0 = bx * 64;

    int r0 = t >> 2,        c0 = ((t & 3) ^ swz(t >> 2)) * 8;
    int r1 = 64 + (t >> 2), c1 = ((t & 3) ^ swz(64 + (t >> 2))) * 8;
    const u16* a0 = A + (size_t)(m0 + r0) * K + c0;
    const u16* a1 = A + (size_t)(m0 + r1) * K + c1;
    const u16* b0 = Wt + (size_t)(n0 + r0) * K + c0;

    auto stage = [&](int k0, int buf) {
        ldsload16(a0 + k0,      &As[buf][wave * 512]);
        ldsload16(a1 + k0,      &As[buf][2048 + wave * 512]);
        ldsload16(b0 + k0,      &Bs[buf][wave * 512]);
        ldsload16(a0 + k0 + 32, &As[buf][4096 + wave * 512]);
        ldsload16(a1 + k0 + 32, &As[buf][6144 + wave * 512]);
        ldsload16(b0 + k0 + 32, &Bs[buf][2048 + wave * 512]);
    };

    f32x4 acc[4][2] = {};
    int row_a = wm + (lane & 15);
    int row_b = wn + (lane & 15);
    int lq = lane >> 4;
    int nchunks = K / 64;

    stage(0, 0);
    __syncthreads();

    for (int ci = 0; ci < nchunks; ++ci) {
        int p = ci & 1;
        bool pref = (ci + 1 < nchunks);
        if (pref) stage((ci + 1) * 64, 1 - p);
        #pragma unroll
        for (int hf = 0; hf < 2; ++hf) {
            bf16x8 af[4], bfr[2];
            #pragma unroll
            for (int i = 0; i < 4; ++i) {
                int r = row_a + i * 16;
                af[i] = *(const bf16x8*)&As[p][hf * 4096 + r * 32 + ((lq ^ swz(r)) * 8)];
            }
            #pragma unroll
            for (int j = 0; j < 2; ++j) {
                int r = row_b + j * 16;
                bfr[j] = *(const bf16x8*)&Bs[p][hf * 2048 + r * 32 + ((lq ^ swz(r)) * 8)];
            }
            #pragma unroll
            for (int i = 0; i < 4; ++i)
                #pragma unroll
                for (int j = 0; j < 2; ++j)
                    acc[i][j] = __builtin_amdgcn_mfma_f32_16x16x32_bf16(
                        af[i], bfr[j], acc[i][j], 0, 0, 0);
        }
        if (pref) __syncthreads();
    }

    int colq = lane & 15, rowq = (lane >> 4) * 4;
    #pragma unroll
    for (int i = 0; i < 4; ++i) {
        #pragma unroll
        for (int rr = 0; rr < 4; ++rr) {
            int m = m0 + wm + i * 16 + rowq + rr;
            size_t mo = (size_t)m * N;
            #pragma unroll
            for (int j = 0; j < 2; ++j) {
                int n = n0 + wn + j * 16 + colq;
                float v = acc[i][j][rr] + bias[n];
                if (act)  v = 0.5f * v * (1.f + erff(v * 0.70710678118654752f));
                outb[mo + n] = f2bf(v);
            }
        }
    }
}

// ---------------- MFMA bf16 GEMM 64x64, bf16 out: used for qkv ---------------
// grid (18, 64) = 1152 = 4.5/CU (1.11x makespan vs gemm4's 1.33x); XCD-swizzled
// so each XCD's contiguous id run reuses its B-panel slice from L2. 32KB LDS.
__global__ __launch_bounds__(256) void mfma_gemm64b(
        const u16* __restrict__ A, const u16* __restrict__ Wt,
        const float* __restrict__ bias, u16* __restrict__ outb,
        int M, int N, int K)
{
    __shared__ u16 As[2][4096];
    __shared__ u16 Bs[2][4096];
    int t = threadIdx.x;
    int lane = t & 63, wave = t >> 6;
    int wm = (wave >> 1) * 32, wn = (wave & 1) * 32;
    int bx, by;
    xcd_remap(bx, by);
    int m0 = by * 64, n0 = bx * 64;

    int r0 = t >> 2, c0 = ((t & 3) ^ swz(t >> 2)) * 8;
    const u16* a0 = A + (size_t)(m0 + r0) * K + c0;
    const u16* b0 = Wt + (size_t)(n0 + r0) * K + c0;

    auto stage = [&](int k0, int buf) {
        ldsload16(a0 + k0,      &As[buf][wave * 512]);
        ldsload16(b0 + k0,      &Bs[buf][wave * 512]);
        ldsload16(a0 + k0 + 32, &As[buf][2048 + wave * 512]);
        ldsload16(b0 + k0 + 32, &Bs[buf][2048 + wave * 512]);
    };

    f32x4 acc[2][2] = {};
    int row_a = wm + (lane & 15);
    int row_b = wn + (lane & 15);
    int lq = lane >> 4;
    int nchunks = K / 64;

    stage(0, 0);
    __syncthreads();

    for (int ci = 0; ci < nchunks; ++ci) {
        int p = ci & 1;
        bool pref = (ci + 1 < nchunks);
        if (pref) stage((ci + 1) * 64, 1 - p);
        #pragma unroll
        for (int hf = 0; hf < 2; ++hf) {
            bf16x8 af[2], bfr[2];
            #pragma unroll
            for (int i = 0; i < 2; ++i) {
                int r = row_a + i * 16;
                af[i] = *(const bf16x8*)&As[p][hf * 2048 + r * 32 + ((lq ^ swz(r)) * 8)];
            }
            #pragma unroll
            for (int j = 0; j < 2; ++j) {
                int r = row_b + j * 16;
                bfr[j] = *(const bf16x8*)&Bs[p][hf * 2048 + r * 32 + ((lq ^ swz(r)) * 8)];
            }
            #pragma unroll
            for (int i = 0; i < 2; ++i)
                #pragma unroll
                for (int j = 0; j < 2; ++j)
                    acc[i][j] = __builtin_amdgcn_mfma_f32_16x16x32_bf16(
                        af[i], bfr[j], acc[i][j], 0, 0, 0);
        }
        if (pref) __syncthreads();
    }

    int colq = lane & 15, rowq = (lane >> 4) * 4;
    #pragma unroll
    for (int i = 0; i < 2; ++i) {
        #pragma unroll
        for (int rr = 0; rr < 4; ++rr) {
            int m = m0 + wm + i * 16 + rowq + rr;
            size_t mo = (size_t)m * N;
            #pragma unroll
            for (int j = 0; j < 2; ++j) {
                int n = n0 + wn + j * 16 + colq;
                outb[mo + n] = f2bf(acc[i][j][rr] + bias[n]);
            }
        }
    }
}

// ---------------- MFMA bf16 GEMM 64x32, BK=128: fused residual epilogue ------
// N=384: grid (12, M/64) = 768 blocks = 3/CU exactly; 48KB LDS -> 3 blocks/CU
// (matches grid, no residency loss). BK=128 halves barrier/drain count in the
// small-K regime (fc2: 24->12 chunks, proj: 6->3). XCD-swizzled.
__global__ __launch_bounds__(256) void mfma_gemm32(
        const u16* __restrict__ A, const u16* __restrict__ Wt,
        const float* __restrict__ bias, const float* __restrict__ posr,
        float* __restrict__ y, int addy, int M, int N, int K)
{
    __shared__ u16 As[2][8192];   // 64 rows x 128 k
    __shared__ u16 Bs[2][4096];   // 32 rows x 128 k
    int t = threadIdx.x;
    int lane = t & 63, wave = t >> 6;
    int wm = (wave >> 1) * 32, wn = (wave & 1) * 16;
    int bx, by;
    xcd_remap(bx, by);
    int m0 = by * 64, n0 = bx * 32;

    int r0 = t >> 2, c0 = ((t & 3) ^ swz(t >> 2)) * 8;
    const u16* a0 = A + (size_t)(m0 + r0) * K + c0;
    int tb = t & 127;
    int rb = tb >> 2, cb = ((tb & 3) ^ swz(tb >> 2)) * 8;
    const u16* b0 = Wt + (size_t)(n0 + rb) * K + cb;

    auto stage = [&](int k0, int buf) {
        ldsload16(a0 + k0,      &As[buf][wave * 512]);
        ldsload16(a0 + k0 + 32, &As[buf][2048 + wave * 512]);
        ldsload16(a0 + k0 + 64, &As[buf][4096 + wave * 512]);
        ldsload16(a0 + k0 + 96, &As[buf][6144 + wave * 512]);
        if (wave < 2) {
            ldsload16(b0 + k0,      &Bs[buf][wave * 512]);
            ldsload16(b0 + k0 + 64, &Bs[buf][2048 + wave * 512]);
        } else {
            ldsload16(b0 + k0 + 32, &Bs[buf][1024 + (wave - 2) * 512]);
            ldsload16(b0 + k0 + 96, &Bs[buf][3072 + (wave - 2) * 512]);
        }
    };

    f32x4 acc[2] = {};
    int row_a = wm + (lane & 15);
    int row_b = wn + (lane & 15);
    int lq = lane >> 4;
    int nchunks = K / 128;

    stage(0, 0);
    __syncthreads();

    for (int ci = 0; ci < nchunks; ++ci) {
        int p = ci & 1;
        bool pref = (ci + 1 < nchunks);
        if (pref) stage((ci + 1) * 128, 1 - p);
        #pragma unroll
        for (int hf = 0; hf < 4; ++hf) {
            bf16x8 af[2], bf0;
            #pragma unroll
            for (int i = 0; i < 2; ++i) {
                int r = row_a + i * 16;
                af[i] = *(const bf16x8*)&As[p][hf * 2048 + r * 32 + ((lq ^ swz(r)) * 8)];
            }
            {
                int r = row_b;
                bf0 = *(const bf16x8*)&Bs[p][hf * 1024 + r * 32 + ((lq ^ swz(r)) * 8)];
            }
            #pragma unroll
            for (int i = 0; i < 2; ++i)
                acc[i] = __builtin_amdgcn_mfma_f32_16x16x32_bf16(
                    af[i], bf0, acc[i], 0, 0, 0);
        }
        if (pref) __syncthreads();
    }

    int colq = lane & 15, rowq = (lane >> 4) * 4;
    #pragma unroll
    for (int i = 0; i < 2; ++i) {
        #pragma unroll
        for (int rr = 0; rr < 4; ++rr) {
            int m = m0 + wm + i * 16 + rowq + rr;
            size_t mo = (size_t)m * N;
            int n = n0 + wn + colq;
            float v = acc[i][rr] + bias[n];
            if (posr) v += posr[(size_t)(m & 1023) * 384 + n];
            if (addy) v += y[mo + n];
            y[mo + n] = v;
        }
    }
}

// ---------------- MFMA flash attention ---------------------------------------
// W==32: global, grid (24, 16, 2) -- key-split 2, unnormalized partials out.
// W==14: windowed, grid (216, 4, 1) -- direct bf16 out; kofs LDS bias-index
//        table replaces incremental coords; fully-invalid query waves skip
//        compute (still stage K/V + hit barriers).
template<int N, int W>
__global__ __launch_bounds__(256) void attn_mfma(const u16* __restrict__ qkv,
        const u16* __restrict__ qkb, const float* __restrict__ rh,
        const float* __restrict__ rw, u16* __restrict__ outb,
        float* __restrict__ opart, float* __restrict__ lpart)
{
    constexpr int JS = (W == 32) ? 64 : 32;
    constexpr int L  = (W == 32) ? 63 : 27;
    constexpr int CTR = W - 1;
    constexpr int KSPAN = (W == 32) ? 512 : 224;
    constexpr int NKT = KSPAN / 32;
    __shared__ u16 KV[11776];  // Ks[2][2048] | Vt[2][2560] | Pb[2560]
    __shared__ u16 bhl[64 * 66];
    __shared__ u16 bwl[64 * 66];
    __shared__ u16 Qt[64 * 66];
    __shared__ unsigned kofs[224];   // W==14: (kh | kw<<16) per key

    u16* Pb = KV + 9216;
    u16* Rt = KV;

    int t = threadIdx.x, lane = t & 63, wave = t >> 6;
    int quad = lane >> 4, l15 = lane & 15;
    int uh = blockIdx.x, qb0 = blockIdx.y * 64;
    int z = (W == 32) ? blockIdx.z : 0;
    int kstart = z * KSPAN;
    int h = uh % HEADS, u = uh / HEADS;
    size_t tbase = (size_t)u * 1024;
    int wb_ = u / 9, wr = u - wb_ * 9;
    int wy = wr / 3, wx = wr - wy * 3;

    auto tok14 = [&](int iy, int ix) -> const u16* {
        int gy = wy * WS + iy, gx = wx * WS + ix;
        if (gy < 32 && gx < 32)
            return qkv + (size_t)(wb_ * 1024 + gy * 32 + gx) * 1152;
        return qkb;
    };
    auto rowptr = [&](int lq2) -> const u16* {   // div-based, prologue only
        if constexpr (W == 32) {
            return qkv + (tbase + lq2) * 1152;
        } else {
            int iy = lq2 / WS, ix = lq2 - iy * WS;
            return tok14(iy, ix);
        }
    };

    // ---- stage Q^T (unscaled) ----
    {
        int q = t & 63, ch0 = (t >> 6) * 16;
        int qc = qb0 + q; if (qc >= N) qc = N - 1;
        const u16* qp = rowptr(qc) + h * 64 + ch0;
        uint4 a = *(const uint4*)qp;
        uint4 b = *(const uint4*)(qp + 8);
        u16 vals[16];
        *(uint4*)vals = a; *(uint4*)(vals + 8) = b;
        #pragma unroll
        for (int c = 0; c < 16; ++c)
            Qt[(ch0 + c) * 66 + q] = ((qb0 + q) < N) ? vals[c] : (u16)0;
    }

    // ---- W==14: key -> (kh,kw) LDS table ----
    if constexpr (W != 32) {
        if (t < 224) {
            int kh = t / WS;
            kofs[t] = (unsigned)kh | ((unsigned)(t - kh * WS) << 16);
        }
    }

    // ---- stage BOTH rel-pos tables (bf16) into Rt ----
    for (int idx = t; idx < JS * 16; idx += 256) {
        int table = (idx >= JS * 8) ? 1 : 0;
        int id2 = idx & (JS * 8 - 1);
        int j = id2 >> 3, cc0 = (id2 & 7) * 8;
        const float* tab = table ? rw : rh;
        u16 tmp[8];
        if (j < L) {
            const float* src = tab + (size_t)j * 64 + cc0;
            #pragma unroll
            for (int c = 0; c < 8; ++c) tmp[c] = f2bf(src[c]);
        } else {
            #pragma unroll
            for (int c = 0; c < 8; ++c) tmp[c] = 0;
        }
        *(uint4*)&Rt[table * JS * 72 + j * 72 + cc0] = *(uint4*)tmp;
    }
    __syncthreads();

    // ---- bias-table MFMAs D = Q . R^T (one phase, both tables) ----
    {
        int tb0 = (W == 32) ? 0 : (wave >> 1);
        int ntb = (W == 32) ? 2 : 1;
        int jt  = (W == 32) ? wave : (wave & 1);
        for (int tt = 0; tt < ntb; ++tt) {
            int table = tb0 + tt;
            const u16* Rtt = Rt + table * JS * 72;
            bf16x8 af0 = *(const bf16x8*)&Rtt[(jt * 16 + l15) * 72 + quad * 8];
            bf16x8 af1 = *(const bf16x8*)&Rtt[(jt * 16 + l15) * 72 + 32 + quad * 8];
            u16* dst = table ? bwl : bhl;
            #pragma unroll
            for (int qt = 0; qt < 4; ++qt) {
                bf16x8 qf0, qf1;
                u16* p0 = (u16*)&qf0; u16* p1 = (u16*)&qf1;
                #pragma unroll
                for (int zz = 0; zz < 8; ++zz) {
                    p0[zz] = Qt[(quad * 8 + zz) * 66 + qt * 16 + l15];
                    p1[zz] = Qt[(32 + quad * 8 + zz) * 66 + qt * 16 + l15];
                }
                f32x4 acc = {};
                acc = __builtin_amdgcn_mfma_f32_16x16x32_bf16(af0, qf0, acc, 0, 0, 0);
                acc = __builtin_amdgcn_mfma_f32_16x16x32_bf16(af1, qf1, acc, 0, 0, 0);
                #pragma unroll
                for (int r = 0; r < 4; ++r)
                    dst[(qt * 16 + l15) * 66 + jt * 16 + quad * 4 + r] = f2bf(acc[r]);
            }
        }
    }
    __syncthreads();

    // ---- per-lane staging coordinates (incremental for W==14) ----
    int skey = (wave * 64 + lane) >> 3;             // K-stage key (0..31)
    int sc8  = ((wave * 64 + lane) & 7) ^ (skey & 7);
    int vkey = t & 31, vch0 = (t >> 5) * 8;         // V-stage key/ch
    int siy = 0, six = 0, viy = 0, vix = 0;
    if constexpr (W != 32) {
        int k0 = kstart + skey;   // kstart==0
        siy = k0 / WS; six = k0 - siy * WS;
        int k1 = kstart + vkey;
        viy = k1 / WS; vix = k1 - viy * WS;
    }
    auto adv = [](int& iy, int& ix) { ix += 4; iy += 2; if (ix >= WS) { ix -= WS; ++iy; } };

    // ---- stage tile 0 into buffer 0 ----
    {
        const u16* kp = (W == 32) ? qkv + (tbase + kstart + skey) * 1152
                                  : tok14(siy, six);
        ldsload16(kp + 384 + h * 64 + sc8 * 8, KV + wave * 512);
        const u16* vp = (W == 32) ? qkv + (tbase + kstart + vkey) * 1152
                                  : tok14(viy, vix);
        uint4 vv = *(const uint4*)(vp + 768 + h * 64 + vch0);
        u16 tmp[8]; *(uint4*)tmp = vv;
        u16* vdst = KV + 4096;
        #pragma unroll
        for (int c = 0; c < 8; ++c) vdst[(vch0 + c) * 40 + vkey] = tmp[c];
        if constexpr (W != 32) { adv(siy, six); adv(viy, vix); }
    }

    // Q^T B-frags (loop-invariant; scale applied to scores)
    bf16x8 qf[2];
    #pragma unroll
    for (int hc = 0; hc < 2; ++hc) {
        u16* qv = (u16*)&qf[hc];
        #pragma unroll
        for (int j = 0; j < 8; ++j)
            qv[j] = Qt[(hc * 32 + quad * 8 + j) * 66 + wave * 16 + l15];
    }
    int qme = wave * 16 + l15;
    // wave-uniform: does this wave's 16-query tile contain any valid query?
    bool wactive = (W == 32) ? true : ((qb0 + wave * 16) < N);
    int qq = qb0 + qme; if (qq >= N) qq = N - 1;
    int qh = qq / W, qw = qq - qh * W;
    int qh13 = qh + CTR, qw13 = qw + CTR;
    float bwreg[2][4];
    if constexpr (W == 32) {
        #pragma unroll
        for (int kc2 = 0; kc2 < 2; ++kc2)
            #pragma unroll
            for (int r = 0; r < 4; ++r) {
                int keyl = kc2 * 16 + quad * 4 + r;
                bwreg[kc2][r] = bf2f(bwl[qme * 66 + (qw - keyl + CTR)]);
            }
    }

    f32x4 of[4] = {};
    float lsum = 0.f;
    __syncthreads();   // tile 0 staged (vmcnt drained)

    for (int kt = 0; kt < NKT; ++kt) {
        int kb = kstart + kt * 32;
        int p = kt & 1;
        const u16* ksp = KV + p * 2048;
        const u16* vtp = KV + 4096 + p * 2560;
        bool pref = (kt + 1 < NKT);
        uint4 vpref;
        if (pref) {
            const u16* kp = (W == 32) ? qkv + (tbase + kb + 32 + skey) * 1152
                                      : tok14(siy, six);
            ldsload16(kp + 384 + h * 64 + sc8 * 8, KV + (1 - p) * 2048 + wave * 512);
            const u16* vp = (W == 32) ? qkv + (tbase + kb + 32 + vkey) * 1152
                                      : tok14(viy, vix);
            vpref = *(const uint4*)(vp + 768 + h * 64 + vch0);
            if constexpr (W != 32) { adv(siy, six); adv(viy, vix); }
        }

        // ---- compute tile kt (skipped by fully-invalid query waves) ----
        if (wactive) {
            f32x4 st[2] = {};
            #pragma unroll
            for (int hc = 0; hc < 2; ++hc) {
                #pragma unroll
                for (int kc2 = 0; kc2 < 2; ++kc2) {
                    int key = kc2 * 16 + l15;
                    int c8 = hc * 4 + quad;
                    int pp = key * 8 + (c8 ^ (key & 7));
                    bf16x8 kf = *(const bf16x8*)&ksp[pp * 8];
                    st[kc2] = __builtin_amdgcn_mfma_f32_16x16x32_bf16(
                        kf, qf[hc], st[kc2], 0, 0, 0);
                }
            }
            float bh_t = 0.f;
            if constexpr (W == 32) bh_t = bf2f(bhl[qme * 66 + (qh - (kb >> 5) + CTR)]);
            #pragma unroll
            for (int kc2 = 0; kc2 < 2; ++kc2) {
                float pv4[4];
                #pragma unroll
                for (int r = 0; r < 4; ++r) {
                    int keyl = kc2 * 16 + quad * 4 + r;
                    float pv;
                    if constexpr (W == 32) {
                        float b = bh_t + bwreg[kc2][r];
                        pv = __expf(fmaf(st[kc2][r], 0.125f, b));
                    } else {
                        unsigned ko = kofs[kb + keyl];
                        float b = bf2f(bhl[qme * 66 + qh13 - (int)(ko & 0xffffu)]) +
                                  bf2f(bwl[qme * 66 + qw13 - (int)(ko >> 16)]);
                        pv = __expf(fmaf(st[kc2][r], 0.125f, b));
                        if (kb + keyl >= N) pv = 0.f;
                    }
                    lsum += pv;
                    pv4[r] = pv;
                }
                uint2 pk;
                pk.x = pk2bf(pv4[0], pv4[1]);
                pk.y = pk2bf(pv4[2], pv4[3]);
                *(uint2*)&Pb[wave * 640 + l15 * 40 + kc2 * 16 + quad * 4] = pk;
            }
            bf16x8 pf = *(const bf16x8*)&Pb[wave * 640 + l15 * 40 + quad * 8];
            #pragma unroll
            for (int ca = 0; ca < 4; ++ca) {
                bf16x8 vf = *(const bf16x8*)&vtp[(ca * 16 + l15) * 40 + quad * 8];
                of[ca] = __builtin_amdgcn_mfma_f32_16x16x32_bf16(
                    vf, pf, of[ca], 0, 0, 0);
            }
        }

        if (pref) {
            u16 tmp[8]; *(uint4*)tmp = vpref;
            u16* vdst = KV + 4096 + (1 - p) * 2560;
            #pragma unroll
            for (int c = 0; c < 8; ++c) vdst[(vch0 + c) * 40 + vkey] = tmp[c];
            __syncthreads();
        }
    }

    lsum += __shfl_xor(lsum, 16);
    lsum += __shfl_xor(lsum, 32);
    int q = qb0 + qme;
    if constexpr (W == 32) {
        // unnormalized partials: O fp32 + l
        size_t ridx = (size_t)z * 24576 + (size_t)uh * 1024 + q;
        float* op = opart + ridx * 64;
        #pragma unroll
        for (int ca = 0; ca < 4; ++ca)
            *(float4*)&op[ca * 16 + quad * 4] = (float4){of[ca][0], of[ca][1],
                                                         of[ca][2], of[ca][3]};
        if (quad == 0) lpart[ridx] = lsum;
    } else {
        float inv = 1.f / lsum;
        if (q < N) {
            int iy = q / WS, ix = q - iy * WS;
            int gy = wy * WS + iy, gx = wx * WS + ix;
            if (gy >= 32 || gx >= 32) return;
            u16* op = outb + (size_t)(wb_ * 1024 + gy * 32 + gx) * 384 + h * 64;
            #pragma unroll
            for (int ca = 0; ca < 4; ++ca) {
                uint2 pk;
                pk.x = pk2bf(of[ca][0] * inv, of[ca][1] * inv);
                pk.y = pk2bf(of[ca][2] * inv, of[ca][3] * inv);
                *(uint2*)&op[ca * 16 + quad * 4] = pk;
            }
        }
    }
}

// ---------------- merge split-key attention partials (x4 vectorized) ---------
__global__ __launch_bounds__(256) void attn_merge_kernel(const float* __restrict__ O,
        const float* __restrict__ Lp, u16* __restrict__ attb)
{
    int gi = blockIdx.x * 256 + threadIdx.x;   // 393216 threads, 4 ch each
    int idx = gi >> 4;                          // uh*1024 + q
    int ch = (gi & 15) * 4;
    float4 o0 = *(const float4*)&O[(size_t)idx * 64 + ch];
    float4 o1 = *(const float4*)&O[((size_t)24576 + idx) * 64 + ch];
    float inv = 1.f / (Lp[idx] + Lp[24576 + idx]);
    int uh = idx >> 10, q = idx & 1023;
    int u = uh / 6, h = uh - u * 6;
    uint2 pk;
    pk.x = pk2bf((o0.x + o1.x) * inv, (o0.y + o1.y) * inv);
    pk.y = pk2bf((o0.z + o1.z) * inv, (o0.w + o1.w) * inv);
    *(uint2*)(attb + ((size_t)(u * 1024 + q)) * 384 + h * 64 + ch) = pk;
}

// ---------------- host helpers ----------------
static inline void launch_gemm(const u16* A, const u16* W, const float* bias,
                               u16* outb, int M, int N, int K, int act,
                               hipStream_t s) {
    dim3 g(N / 64, M / 128, 1);
    mfma_gemm4<<<g, 256, 0, s>>>(A, W, bias, outb, M, N, K, act);
}

// BM=64/BN=64 bf16-out GEMM (qkv): grid (18, 64) = 1152 = 4.5/CU, swizzled
static inline void launch_gemm64b(const u16* A, const u16* W, const float* bias,
                                  u16* outb, int M, int N, int K, hipStream_t s) {
    dim3 g(N / 64, M / 64, 1);
    mfma_gemm64b<<<g, 256, 0, s>>>(A, W, bias, outb, M, N, K);
}

// BM=64/BN=32/BK=128 fused-residual GEMM: grid (N/32, M/64) = 768 (balanced)
static inline void launch_gemm32(const u16* A, const u16* W, const float* bias,
                                 const float* posr, float* y, int addy,
                                 int M, int N, int K, hipStream_t s) {
    dim3 g(N / 32, M / 64, 1);
    mfma_gemm32<<<g, 256, 0, s>>>(A, W, bias, posr, y, addy, M, N, K);
}

extern "C" void kernel_launch(void* const* d_in, const int* in_sizes, int n_in,
                              void* d_out, int out_size, void* d_ws, size_t ws_size,
                              hipStream_t stream) {
    const float* x      = (const float*)d_in[0];
    const float* patchw = (const float*)d_in[1];
    const float* patchb = (const float*)d_in[2];
    const float* pos    = (const float*)d_in[3];
    const float* n1w    = (const float*)d_in[4];
    const float* n1b    = (const float*)d_in[5];
    const float* qkvw   = (const float*)d_in[6];
    const float* qkvb   = (const float*)d_in[7];
    const float* pw     = (const float*)d_in[8];
    const float* pb     = (const float*)d_in[9];
    const float* n2w    = (const float*)d_in[10];
    const float* n2b    = (const float*)d_in[11];
    const float* f1w    = (const float*)d_in[12];
    const float* f1b    = (const float*)d_in[13];
    const float* f2w    = (const float*)d_in[14];
    const float* f2b    = (const float*)d_in[15];
    const float* rph    = (const float*)d_in[16];
    const float* rpw    = (const float*)d_in[17];
    float* out = (float*)d_out;

    // workspace layout (unchanged). Overlays cover only dead buffers:
    //  colb = rsrv (im2col, patch phase only)
    //  Opart = mlpb (global-attn phase), Lpart = lnb (dead post-qkv)
    float* y   = (float*)d_ws;                  // 1,572,864 f32
    u16* attb  = (u16*)(y + 1572864);           // 1,572,864 u16 (token layout)
    u16* mlpb  = attb + 1572864;                // 6,291,456 u16
    u16* lnb   = mlpb + 6291456;                // 1,572,864 u16
    u16* qkvx  = lnb + 1572864;                 // 4,718,592 u16 (4096x1152)
    u16* rsrv  = qkvx + 4718592;                // 7,864,320 u16
    u16* wb    = rsrv + 7864320;                // 10,918,656 u16 (weights + qkv bias)
    float* posr = (float*)(wb + 10918656);      //   393,216 f32

    u16* colb  = rsrv;                          // overlay: im2col 3,145,728 u16
    float* Opart   = (float*)mlpb;              // 2x24576x64 f32 = 12,582,912 B
    float* Lpart   = (float*)lnb;               // 2x24576 f32

    u16* wb_patch = wb;
    u16* wb_qkv   = wb + 294912;
    u16* wb_pw    = wb + 2949120;
    u16* wb_f1    = wb + 3833856;
    u16* wb_f2    = wb + 7372800;
    u16* wqb      = wb + 10911744;              // bf16 qkv bias, 6 x 1152

    setup_kernel<<<(14457600 / 4 + 255) / 256, 256, 0, stream>>>(
        patchw, qkvw, pw, f1w, f2w, qkvb, wb, pos, posr, x, colb);

    // patch embed: fused bias + pos-embed -> y (f32), then LN -> lnb
    launch_gemm32(colb, wb_patch, patchb, posr, y, 0, NTOK, 384, 768, stream);
    ln_kernel<<<1024, 256, 0, stream>>>(y, n1w, n1b, lnb);

    for (int i = 0; i < 6; ++i) {
        bool windowed = (i == 0 || i == 1 || i == 3 || i == 4);
        const float* rh = rph + (size_t)i * 63 * 64;
        const float* rw = rpw + (size_t)i * 63 * 64;
        // qkv: balanced 1152-block 64x64 GEMM (4.5/CU), XCD-swizzled
        launch_gemm64b(lnb, wb_qkv + (size_t)i * 442368, qkvb + i * 1152,
                       qkvx, NTOK, 1152, 384, stream);
        if (windowed) {
            attn_mfma<WTOK, WS><<<dim3(NWIN * HEADS, 4, 1), 256, 0, stream>>>(
                qkvx, wqb + i * 1152, rh, rw, attb, nullptr, nullptr);
        } else {
            attn_mfma<1024, 32><<<dim3(B_SZ * HEADS, 16, 2), 256, 0, stream>>>(
                qkvx, wqb + i * 1152, rh, rw, nullptr, Opart, Lpart);
            attn_merge_kernel<<<1536, 256, 0, stream>>>(Opart, Lpart, attb);
        }
        // proj: fused bias + residual accumulate onto y
        launch_gemm32(attb, wb_pw + (size_t)i * 147456, pb + i * 384,
                      nullptr, y, 1, NTOK, 384, 384, stream);
        ln_kernel<<<1024, 256, 0, stream>>>(y, n2w + i * 384, n2b + i * 384, lnb);
        launch_gemm(lnb, wb_f1 + (size_t)i * 589824, f1b + i * 1536,
                    mlpb, NTOK, 1536, 384, 1, stream);
        // fc2: fused bias + residual accumulate onto y
        launch_gemm32(mlpb, wb_f2 + (size_t)i * 589824, f2b + i * 384,
                      nullptr, y, 1, NTOK, 384, 1536, stream);
        if (i < 5)
            ln_kernel<<<1024, 256, 0, stream>>>(y, n1w + (i + 1) * 384,
                                                n1b + (i + 1) * 384, lnb);
        else
            out_transpose<<<dim3(6, 64), 256, 0, stream>>>(y, out);
    }
}